// Round 4
// baseline (852.932 us; speedup 1.0000x reference)
//
#include <hip/hip_runtime.h>
#include <stdint.h>

typedef unsigned short u16;
typedef short bf16x8 __attribute__((ext_vector_type(8)));
typedef float f32x4 __attribute__((ext_vector_type(4)));

#define NTOK 100352      // B*H*W tokens
#define NWIN 2048        // B * 64 windows
#define CC 256
#define NHEAD 8
#define HDIM 32
#define NWT 49           // tokens per window
#define MLPD 1024
#define ATT_SCALE 0.17677669529663687f  // 32^-0.5

__device__ __forceinline__ u16 f2b(float f) {
  union { float f; uint32_t u; } c; c.f = f;
  return (u16)((c.u + 0x7fffu + ((c.u >> 16) & 1u)) >> 16);
}
__device__ __forceinline__ float b2f(u16 h) {
  union { uint32_t u; float f; } c; c.u = ((uint32_t)h) << 16;
  return c.f;
}

__device__ __forceinline__ void gload_lds16(const void* g, void* l) {
  __builtin_amdgcn_global_load_lds((const __attribute__((address_space(1))) void*)g,
                                   (__attribute__((address_space(3))) void*)l, 16, 0, 0);
}

// ---------------- weight convert + transpose: w[K][N] fp32 -> wT[N][K] bf16
__global__ __launch_bounds__(256) void wconv_k(const float* __restrict__ w,
                                               u16* __restrict__ wT, int K, int N) {
  int i = blockIdx.x * 256 + threadIdx.x;
  if (i < K * N) {
    int k = i / N, n = i % N;
    wT[(size_t)n * K + k] = f2b(w[i]);
  }
}

// ---------------- relative-position bias LUT: lut[h][m][n] (64x64 padded, 0 outside 49)
__global__ __launch_bounds__(256) void bias_lut_k(const float* __restrict__ rpb,
                                                  float* __restrict__ lut) {
  int i = blockIdx.x * 256 + threadIdx.x;
  if (i >= 8 * 64 * 64) return;
  int h = i >> 12, m = (i >> 6) & 63, n = i & 63;
  float v = 0.f;
  if (m < 49 && n < 49) {
    int i1 = n / 7, j1 = n % 7;   // query coords
    int i2 = m / 7, j2 = m % 7;   // key coords
    v = rpb[((i1 - i2 + 6) * 13 + (j1 - j2 + 6)) * 8 + h];
  }
  lut[i] = v;
}

// ---------------- LN (+ optional shift/window-partition) -> bf16 tokens
template<bool PART>
__global__ __launch_bounds__(256)
void ln_k(const float* __restrict__ x, const float* __restrict__ g,
          const float* __restrict__ be, u16* __restrict__ out) {
  int token = blockIdx.x * 4 + (threadIdx.x >> 6);
  int lane = threadIdx.x & 63;
  size_t src;
  if (PART) {
    int win = token / 49, nn = token % 49;
    int b = win >> 6, wh = (win >> 3) & 7, ww = win & 7;
    int i = nn / 7, j = nn % 7;
    int h = wh * 7 + i + 3; if (h >= 56) h -= 56;
    int w = ww * 7 + j + 3; if (w >= 56) w -= 56;
    src = ((size_t)((b * 56 + h) * 56 + w)) * CC;
  } else {
    src = (size_t)token * CC;
  }
  f32x4 v = *(const f32x4*)&x[src + lane * 4];
  float s1 = v[0] + v[1] + v[2] + v[3];
  float s2 = v[0]*v[0] + v[1]*v[1] + v[2]*v[2] + v[3]*v[3];
#pragma unroll
  for (int o = 32; o; o >>= 1) { s1 += __shfl_xor(s1, o); s2 += __shfl_xor(s2, o); }
  float mean = s1 * (1.f / 256.f);
  float var = s2 * (1.f / 256.f) - mean * mean;
  float rstd = rsqrtf(var + 1e-5f);
  f32x4 gv = *(const f32x4*)&g[lane * 4];
  f32x4 bv = *(const f32x4*)&be[lane * 4];
  float y0 = (v[0]-mean)*rstd*gv[0] + bv[0];
  float y1 = (v[1]-mean)*rstd*gv[1] + bv[1];
  float y2 = (v[2]-mean)*rstd*gv[2] + bv[2];
  float y3 = (v[3]-mean)*rstd*gv[3] + bv[3];
  uint32_t lo = f2b(y0) | ((uint32_t)f2b(y1) << 16);
  uint32_t hi = f2b(y2) | ((uint32_t)f2b(y3) << 16);
  *(uint2*)&out[(size_t)token * CC + lane * 4] = make_uint2(lo, hi);
}

// ---------------- GEMM: C = A(MxK,bf16) * BT(NxK,bf16)^T + bias, epilogue variants
#define BM 128
#define BN 128
#define BK 32
enum { EPI_QKV = 0, EPI_PROJ = 1 };

template<int EPI>
__global__ __launch_bounds__(256)
void gemm_k(const u16* __restrict__ A, const u16* __restrict__ BT,
            const float* __restrict__ bias, int K,
            void* __restrict__ p0, const void* __restrict__ p1) {
  __shared__ u16 aL[BM * BK];
  __shared__ u16 bL[BN * BK];
  const int tid = threadIdx.x;
  const int lane = tid & 63;
  const int wv = tid >> 6;
  const int wm = wv >> 1, wn = wv & 1;

  // T1: XCD-aware block swizzle (nwg divisible by 8 for all our grids)
  int bx = blockIdx.x, by = blockIdx.y;
  {
    int nwg = gridDim.x * gridDim.y;
    int lin = by * gridDim.x + bx;
    int wg = (lin & 7) * (nwg >> 3) + (lin >> 3);
    bx = wg % gridDim.x;
    by = wg / gridDim.x;
  }
  const long m0 = (long)by * BM;
  const int n0 = bx * BN;

  f32x4 acc[4][4] = {};

  const int r15 = lane & 15;
  const int kc = lane >> 4;
  const int rcsw = kc ^ ((r15 >> 1) & 3);   // swizzled 16B-chunk for ds_read

  for (int kt = 0; kt < K; kt += BK) {
#pragma unroll
    for (int it = 0; it < 2; ++it) {
      int slot = tid + 256 * it;
      int row = slot >> 2, c = slot & 3;
      int cs = c ^ ((row >> 1) & 3);
      gload_lds16(&A[(m0 + row) * K + kt + cs * 8], &aL[slot * 8]);
    }
#pragma unroll
    for (int it = 0; it < 2; ++it) {
      int slot = tid + 256 * it;
      int row = slot >> 2, c = slot & 3;
      int cs = c ^ ((row >> 1) & 3);
      gload_lds16(&BT[(size_t)(n0 + row) * K + kt + cs * 8], &bL[slot * 8]);
    }
    __syncthreads();
    bf16x8 af[4], bfr[4];
#pragma unroll
    for (int m = 0; m < 4; ++m)
      af[m] = *(const bf16x8*)&aL[(wm * 64 + m * 16 + r15) * BK + rcsw * 8];
#pragma unroll
    for (int n = 0; n < 4; ++n)
      bfr[n] = *(const bf16x8*)&bL[(wn * 64 + n * 16 + r15) * BK + rcsw * 8];
#pragma unroll
    for (int m = 0; m < 4; ++m)
#pragma unroll
      for (int n = 0; n < 4; ++n)
        acc[m][n] = __builtin_amdgcn_mfma_f32_16x16x32_bf16(af[m], bfr[n], acc[m][n], 0, 0, 0);
    __syncthreads();
  }

  // epilogue: C/D layout col = lane&15, row = (lane>>4)*4 + j
#pragma unroll
  for (int m = 0; m < 4; ++m) {
    int rb = wm * 64 + m * 16 + (lane >> 4) * 4;
#pragma unroll
    for (int n = 0; n < 4; ++n) {
      int col = n0 + wn * 64 + n * 16 + (lane & 15);
      float bv = bias[col];
#pragma unroll
      for (int j = 0; j < 4; ++j) {
        int grow = (int)m0 + rb + j;
        float v = acc[m][n][j] + bv;
        if (EPI == EPI_QKV) {
          v = fmaxf(v, 0.f);
          int s = col >> 8, head = (col >> 5) & 7, d = col & 31;
          if (s == 0) v *= ATT_SCALE;   // fold softmax scale into q
          int win = grow / 49, nn = grow % 49;
          u16* dst = (u16*)p0 + (size_t)s * ((size_t)NTOK * CC);
          dst[(((size_t)(win * NHEAD + head)) * NWT + nn) * HDIM + d] = f2b(v);
        } else {  // EPI_PROJ: reverse shift + residual, fp32 out
          int win = grow / 49, nn = grow % 49;
          int b = win >> 6, wh = (win >> 3) & 7, ww = win & 7;
          int i = nn / 7, jj = nn % 7;
          int h = wh * 7 + i + 3; if (h >= 56) h -= 56;
          int w = ww * 7 + jj + 3; if (w >= 56) w -= 56;
          size_t pix = (size_t)((b * 56 + h) * 56 + w);
          float o = ((const float*)p1)[pix * CC + col] + v;
          ((float*)p0)[pix * CC + col] = o;
        }
      }
    }
  }
}

// ---------------- fused MLP v2: out = x2 + gelu(xn @ fc1 + b1) @ fc2 + b2
// v1 failed from VGPR spills (launch_bounds(512,2) capped at 128 < ~190 demand).
// v2: (512,1) -> 256-VGPR budget, no spills; double-buffered h chunk in LDS with
// [S2(c); S1(c+1)] per barrier segment so stage-2 MFMAs hide stage-1 L2 loads.
#define LDH 134   // u16 pitch: 67 dwords (odd) -> writes/reads spread across all banks
__global__ __launch_bounds__(512, 1)
void mlp_k(const u16* __restrict__ xn, const u16* __restrict__ fc1T,
           const u16* __restrict__ fc2T, const float* __restrict__ b1,
           const float* __restrict__ b2, const float* __restrict__ x2,
           float* __restrict__ outp) {
  __shared__ u16 hL[2][128][LDH];
  const int tid = threadIdx.x;
  const int lane = tid & 63;
  const int wv = tid >> 6;
  const int c = lane & 15;
  const int g = lane >> 4;
  const long m0 = (long)blockIdx.x * 128;

  const int wn1 = wv >> 2;     // stage1: n-half (0..1), 64 mlp-cols
  const int wr1 = wv & 3;      // stage1: r-quarter (0..3), 32 rows
  const int wr2 = wv >> 2;     // stage2: r-half (0..1), 64 rows
  const int wn2 = wv & 3;      // stage2: nout-quarter (0..3), 64 cols

  f32x4 oacc[4][4] = {};

  // ---- stage 1 for chunk hc: h[r][nbase..nbase+64) = gelu(fc1 xn + b1), S^T layout
  auto stage1 = [&](int hc) {
    const int nbase = hc * 128 + wn1 * 64;
    f32x4 acc1[4][2] = {};
#pragma unroll
    for (int kk = 0; kk < 8; ++kk) {
      bf16x8 af[4], xf[2];
#pragma unroll
      for (int nt = 0; nt < 4; ++nt)
        af[nt] = *(const bf16x8*)&fc1T[(size_t)(nbase + nt * 16 + c) * 256 + kk * 32 + g * 8];
#pragma unroll
      for (int rt = 0; rt < 2; ++rt)
        xf[rt] = *(const bf16x8*)&xn[(m0 + wr1 * 32 + rt * 16 + c) * 256 + kk * 32 + g * 8];
#pragma unroll
      for (int nt = 0; nt < 4; ++nt)
#pragma unroll
        for (int rt = 0; rt < 2; ++rt)
          acc1[nt][rt] = __builtin_amdgcn_mfma_f32_16x16x32_bf16(af[nt], xf[rt], acc1[nt][rt], 0, 0, 0);
    }
    u16(*hb)[LDH] = hL[hc & 1];
#pragma unroll
    for (int nt = 0; nt < 4; ++nt) {
      f32x4 bv = *(const f32x4*)&b1[nbase + nt * 16 + g * 4];
#pragma unroll
      for (int rt = 0; rt < 2; ++rt) {
        int r = wr1 * 32 + rt * 16 + c;
        float v0 = acc1[nt][rt][0] + bv[0];
        float v1 = acc1[nt][rt][1] + bv[1];
        float v2 = acc1[nt][rt][2] + bv[2];
        float v3 = acc1[nt][rt][3] + bv[3];
        v0 = 0.5f * v0 * (1.f + erff(v0 * 0.70710678118654752f));
        v1 = 0.5f * v1 * (1.f + erff(v1 * 0.70710678118654752f));
        v2 = 0.5f * v2 * (1.f + erff(v2 * 0.70710678118654752f));
        v3 = 0.5f * v3 * (1.f + erff(v3 * 0.70710678118654752f));
        uint32_t w0 = (uint32_t)f2b(v0) | ((uint32_t)f2b(v1) << 16);
        uint32_t w1 = (uint32_t)f2b(v2) | ((uint32_t)f2b(v3) << 16);
        *(uint2*)&hb[r][wn1 * 64 + nt * 16 + g * 4] = make_uint2(w0, w1);
      }
    }
  };

  // ---- stage 2 for chunk hc: oacc += h_chunk @ fc2T[:, hc*128..)
  auto stage2 = [&](int hc) {
    u16(*hb)[LDH] = hL[hc & 1];
#pragma unroll
    for (int kk = 0; kk < 4; ++kk) {
      bf16x8 ha[4], wb[4];
#pragma unroll
      for (int rt = 0; rt < 4; ++rt)
        ha[rt] = *(const bf16x8*)&hb[wr2 * 64 + rt * 16 + c][kk * 32 + g * 8];
#pragma unroll
      for (int nt = 0; nt < 4; ++nt)
        wb[nt] = *(const bf16x8*)&fc2T[(size_t)(wn2 * 64 + nt * 16 + c) * 1024 + hc * 128 + kk * 32 + g * 8];
#pragma unroll
      for (int rt = 0; rt < 4; ++rt)
#pragma unroll
        for (int nt = 0; nt < 4; ++nt)
          oacc[rt][nt] = __builtin_amdgcn_mfma_f32_16x16x32_bf16(ha[rt], wb[nt], oacc[rt][nt], 0, 0, 0);
    }
  };

  stage1(0);
  __syncthreads();
  for (int hc = 0; hc < 8; ++hc) {
    stage2(hc);
    if (hc < 7) stage1(hc + 1);
    __syncthreads();
  }

  // epilogue: out = x2 + oacc + b2
#pragma unroll
  for (int rt = 0; rt < 4; ++rt) {
    long rb = m0 + wr2 * 64 + rt * 16 + g * 4;
#pragma unroll
    for (int nt = 0; nt < 4; ++nt) {
      int col = wn2 * 64 + nt * 16 + c;
      float bv = b2[col];
#pragma unroll
      for (int j = 0; j < 4; ++j) {
        size_t idx = (size_t)(rb + j) * CC + col;
        outp[idx] = x2[idx] + oacc[rt][nt][j] + bv;
      }
    }
  }
}

// ---------------- MFMA window attention: 1 wave = 1 (window, head), 4 waves/block
__global__ __launch_bounds__(256)
void attn_mfma_k(const u16* __restrict__ q, const u16* __restrict__ k2,
                 const u16* __restrict__ v2, const float* __restrict__ lut,
                 u16* __restrict__ out) {
  __shared__ u16 P_lds[4][64 * 72];
  const int tid = threadIdx.x;
  const int wv = tid >> 6;
  const int lane = tid & 63;
  const int c = lane & 15;
  const int g = lane >> 4;
  const int blk = blockIdx.x * 4 + wv;   // (window, head) id
  const int head = blk & 7;
  const int win = blk >> 3;
  const int wimg = win & 63;
  const int wh = wimg >> 3, ww = wimg & 7;
  const size_t base = (size_t)blk * (NWT * HDIM);
  u16* Pw = P_lds[wv];

  bf16x8 kf[4], qf[4];
#pragma unroll
  for (int t = 0; t < 4; ++t) {
    kf[t] = *(const bf16x8*)&k2[base + (size_t)(t * 16 + c) * HDIM + g * 8];
    qf[t] = *(const bf16x8*)&q [base + (size_t)(t * 16 + c) * HDIM + g * 8];
  }
  bf16x8 vf[2][2];
#pragma unroll
  for (int kcc = 0; kcc < 2; ++kcc)
#pragma unroll
    for (int td = 0; td < 2; ++td)
#pragma unroll
      for (int jj = 0; jj < 8; ++jj) {
        int m = kcc * 32 + g * 8 + jj;
        m = m < 49 ? m : 48;
        vf[kcc][td][jj] = (short)v2[base + (size_t)m * HDIM + td * 16 + c];
      }

  f32x4 acc[4][4] = {};
#pragma unroll
  for (int tm = 0; tm < 4; ++tm)
#pragma unroll
    for (int tn = 0; tn < 4; ++tn)
      acc[tm][tn] = __builtin_amdgcn_mfma_f32_16x16x32_bf16(kf[tm], qf[tn], acc[tm][tn], 0, 0, 0);

  const float* lrow = &lut[(size_t)head * 64 * 64];
  int Ln[4];
#pragma unroll
  for (int tn = 0; tn < 4; ++tn) {
    int n = tn * 16 + c;
    int i1 = (n * 9363) >> 16;
    int j1 = n - i1 * 7;
    int rh = (wh < 7) ? 0 : (i1 < 4 ? 1 : 2);
    int rw = (ww < 7) ? 0 : (j1 < 4 ? 1 : 2);
    Ln[tn] = rh * 3 + rw;
  }
  float colmax[4] = {0.f, 0.f, 0.f, 0.f};
#pragma unroll
  for (int tm = 0; tm < 4; ++tm)
#pragma unroll
    for (int j = 0; j < 4; ++j) {
      int m = tm * 16 + g * 4 + j;
      int i2 = (m * 9363) >> 16;
      int j2 = m - i2 * 7;
      int rh = (wh < 7) ? 0 : (i2 < 4 ? 1 : 2);
      int rw = (ww < 7) ? 0 : (j2 < 4 ? 1 : 2);
      int Lm = rh * 3 + rw;
#pragma unroll
      for (int tn = 0; tn < 4; ++tn) {
        float s = acc[tm][tn][j] + lrow[m * 64 + tn * 16 + c];
        s = fmaxf(s, 0.f);
        if (Lm != Ln[tn]) s = 0.f;
        acc[tm][tn][j] = s;
        colmax[tn] = fmaxf(colmax[tn], s);
      }
    }
#pragma unroll
  for (int tn = 0; tn < 4; ++tn) {
    colmax[tn] = fmaxf(colmax[tn], __shfl_xor(colmax[tn], 16));
    colmax[tn] = fmaxf(colmax[tn], __shfl_xor(colmax[tn], 32));
  }
  float colsum[4] = {0.f, 0.f, 0.f, 0.f};
#pragma unroll
  for (int tm = 0; tm < 4; ++tm)
#pragma unroll
    for (int j = 0; j < 4; ++j) {
      int m = tm * 16 + g * 4 + j;
      bool mvalid = (m < NWT);
#pragma unroll
      for (int tn = 0; tn < 4; ++tn) {
        float e = mvalid ? __expf(acc[tm][tn][j] - colmax[tn]) : 0.f;
        acc[tm][tn][j] = e;
        colsum[tn] += e;
      }
    }
#pragma unroll
  for (int tn = 0; tn < 4; ++tn) {
    colsum[tn] += __shfl_xor(colsum[tn], 16);
    colsum[tn] += __shfl_xor(colsum[tn], 32);
    colsum[tn] = 1.f / colsum[tn];
  }

#pragma unroll
  for (int tn = 0; tn < 4; ++tn) {
    int n = tn * 16 + c;
#pragma unroll
    for (int tm = 0; tm < 4; ++tm) {
      float r = colsum[tn];
      uint32_t w0 = (uint32_t)f2b(acc[tm][tn][0] * r) | ((uint32_t)f2b(acc[tm][tn][1] * r) << 16);
      uint32_t w1 = (uint32_t)f2b(acc[tm][tn][2] * r) | ((uint32_t)f2b(acc[tm][tn][3] * r) << 16);
      *(uint2*)&Pw[n * 72 + tm * 16 + g * 4] = make_uint2(w0, w1);
    }
  }

  f32x4 oacc[4][2] = {};
#pragma unroll
  for (int kcc = 0; kcc < 2; ++kcc) {
    bf16x8 pf[4];
#pragma unroll
    for (int tr = 0; tr < 4; ++tr)
      pf[tr] = *(const bf16x8*)&Pw[(tr * 16 + c) * 72 + kcc * 32 + g * 8];
#pragma unroll
    for (int tr = 0; tr < 4; ++tr)
#pragma unroll
      for (int td = 0; td < 2; ++td)
        oacc[tr][td] = __builtin_amdgcn_mfma_f32_16x16x32_bf16(pf[tr], vf[kcc][td], oacc[tr][td], 0, 0, 0);
  }

#pragma unroll
  for (int tr = 0; tr < 4; ++tr)
#pragma unroll
    for (int j = 0; j < 4; ++j) {
      int n = tr * 16 + g * 4 + j;
      if (n < NWT) {
#pragma unroll
        for (int td = 0; td < 2; ++td) {
          int d = td * 16 + c;
          out[((size_t)(win * NWT + n)) * CC + head * HDIM + d] =
              f2b(fmaxf(oacc[tr][td][j], 0.f));
        }
      }
    }
}

// ---------------- launch
extern "C" void kernel_launch(void* const* d_in, const int* in_sizes, int n_in,
                              void* d_out, int out_size, void* d_ws, size_t ws_size,
                              hipStream_t stream) {
  const float* x      = (const float*)d_in[0];
  const float* gamma1 = (const float*)d_in[1];
  const float* beta1  = (const float*)d_in[2];
  const float* w_qkv  = (const float*)d_in[3];
  const float* b_qkv  = (const float*)d_in[4];
  const float* rpb    = (const float*)d_in[5];
  const float* w_proj = (const float*)d_in[6];
  const float* b_proj = (const float*)d_in[7];
  const float* gamma2 = (const float*)d_in[8];
  const float* beta2  = (const float*)d_in[9];
  const float* w_fc1  = (const float*)d_in[10];
  const float* b_fc1  = (const float*)d_in[11];
  const float* w_fc2  = (const float*)d_in[12];
  const float* b_fc2  = (const float*)d_in[13];
  float* out = (float*)d_out;

  char* ws = (char*)d_ws;
  size_t off = 0;
  auto alloc = [&](size_t bytes) { void* p = ws + off; off = (off + bytes + 255) & ~(size_t)255; return p; };

  u16* wqkvT = (u16*)alloc(768 * 256 * 2);
  u16* wprojT = (u16*)alloc(256 * 256 * 2);
  u16* wfc1T = (u16*)alloc(1024 * 256 * 2);
  u16* wfc2T = (u16*)alloc(256 * 1024 * 2);
  float* lut = (float*)alloc(8 * 64 * 64 * 4);
  // region2: xw -> attn_out -> xn2 (lifetimes disjoint)
  u16* region2 = (u16*)alloc((size_t)NTOK * CC * 2);
  // region1: q|k|v (3x 51.4MB); after attention reused as x2 (fp32, 102.8MB)
  char* region1 = (char*)alloc((size_t)3 * NTOK * CC * 2);

  u16* xw = region2;
  u16* qb = (u16*)region1;
  u16* kb = qb + (size_t)NTOK * CC;
  u16* vb = kb + (size_t)NTOK * CC;
  u16* attn_out = region2;
  float* x2 = (float*)region1;
  u16* xn2 = region2;

  if (ws_size < off) return;  // insufficient scratch: fail visibly

  wconv_k<<<(256 * 768 + 255) / 256, 256, 0, stream>>>(w_qkv, wqkvT, 256, 768);
  wconv_k<<<(256 * 256 + 255) / 256, 256, 0, stream>>>(w_proj, wprojT, 256, 256);
  wconv_k<<<(256 * 1024 + 255) / 256, 256, 0, stream>>>(w_fc1, wfc1T, 256, 1024);
  wconv_k<<<(1024 * 256 + 255) / 256, 256, 0, stream>>>(w_fc2, wfc2T, 1024, 256);
  bias_lut_k<<<(8 * 64 * 64) / 256, 256, 0, stream>>>(rpb, lut);

  // LN1 + shift + partition
  ln_k<true><<<NTOK / 4, 256, 0, stream>>>(x, gamma1, beta1, xw);

  // QKV GEMM: M=100352, N=768, K=256 (XCD-swizzled)
  gemm_k<EPI_QKV><<<dim3(768 / BN, NTOK / BM), 256, 0, stream>>>(
      xw, wqkvT, b_qkv, 256, (void*)qb, nullptr);

  // fused MFMA window attention: 1 wave per (window, head)
  attn_mfma_k<<<NWIN * NHEAD / 4, 256, 0, stream>>>(qb, kb, vb, lut, attn_out);

  // proj GEMM + reverse shift + residual: M=100352, N=256, K=256
  gemm_k<EPI_PROJ><<<dim3(256 / BN, NTOK / BM), 256, 0, stream>>>(
      attn_out, wprojT, b_proj, 256, (void*)x2, (const void*)x);

  // LN2
  ln_k<false><<<NTOK / 4, 256, 0, stream>>>(x2, gamma2, beta2, xn2);

  // fused MLP v2 (fc1 + GELU + fc2 + residual), h never hits HBM
  mlp_k<<<NTOK / 128, 512, 0, stream>>>(xn2, wfc1T, wfc2T, b_fc1, b_fc2, x2, out);
}

// Round 5
// 649.180 us; speedup vs baseline: 1.3139x; 1.3139x over previous
//
#include <hip/hip_runtime.h>
#include <stdint.h>

typedef unsigned short u16;
typedef short bf16x8 __attribute__((ext_vector_type(8)));
typedef float f32x4 __attribute__((ext_vector_type(4)));

#define NTOK 100352      // B*H*W tokens
#define NWIN 2048        // B * 64 windows
#define CC 256
#define NHEAD 8
#define HDIM 32
#define NWT 49           // tokens per window
#define MLPD 1024
#define ATT_SCALE 0.17677669529663687f  // 32^-0.5

__device__ __forceinline__ u16 f2b(float f) {
  union { float f; uint32_t u; } c; c.f = f;
  return (u16)((c.u + 0x7fffu + ((c.u >> 16) & 1u)) >> 16);
}
__device__ __forceinline__ float b2f(u16 h) {
  union { uint32_t u; float f; } c; c.u = ((uint32_t)h) << 16;
  return c.f;
}

__device__ __forceinline__ void gload_lds16(const void* g, void* l) {
  __builtin_amdgcn_global_load_lds((const __attribute__((address_space(1))) void*)g,
                                   (__attribute__((address_space(3))) void*)l, 16, 0, 0);
}

// ---------------- weight convert + transpose: w[K][N] fp32 -> wT[N][K] bf16
__global__ __launch_bounds__(256) void wconv_k(const float* __restrict__ w,
                                               u16* __restrict__ wT, int K, int N) {
  int i = blockIdx.x * 256 + threadIdx.x;
  if (i < K * N) {
    int k = i / N, n = i % N;
    wT[(size_t)n * K + k] = f2b(w[i]);
  }
}

// ---------------- relative-position bias LUT: lut[h][m][n] (64x64 padded, 0 outside 49)
__global__ __launch_bounds__(256) void bias_lut_k(const float* __restrict__ rpb,
                                                  float* __restrict__ lut) {
  int i = blockIdx.x * 256 + threadIdx.x;
  if (i >= 8 * 64 * 64) return;
  int h = i >> 12, m = (i >> 6) & 63, n = i & 63;
  float v = 0.f;
  if (m < 49 && n < 49) {
    int i1 = n / 7, j1 = n % 7;   // query coords
    int i2 = m / 7, j2 = m % 7;   // key coords
    v = rpb[((i1 - i2 + 6) * 13 + (j1 - j2 + 6)) * 8 + h];
  }
  lut[i] = v;
}

// ---------------- LN (+ optional shift/window-partition) -> bf16 tokens
template<bool PART>
__global__ __launch_bounds__(256)
void ln_k(const float* __restrict__ x, const float* __restrict__ g,
          const float* __restrict__ be, u16* __restrict__ out) {
  int token = blockIdx.x * 4 + (threadIdx.x >> 6);
  int lane = threadIdx.x & 63;
  size_t src;
  if (PART) {
    int win = token / 49, nn = token % 49;
    int b = win >> 6, wh = (win >> 3) & 7, ww = win & 7;
    int i = nn / 7, j = nn % 7;
    int h = wh * 7 + i + 3; if (h >= 56) h -= 56;
    int w = ww * 7 + j + 3; if (w >= 56) w -= 56;
    src = ((size_t)((b * 56 + h) * 56 + w)) * CC;
  } else {
    src = (size_t)token * CC;
  }
  f32x4 v = *(const f32x4*)&x[src + lane * 4];
  float s1 = v[0] + v[1] + v[2] + v[3];
  float s2 = v[0]*v[0] + v[1]*v[1] + v[2]*v[2] + v[3]*v[3];
#pragma unroll
  for (int o = 32; o; o >>= 1) { s1 += __shfl_xor(s1, o); s2 += __shfl_xor(s2, o); }
  float mean = s1 * (1.f / 256.f);
  float var = s2 * (1.f / 256.f) - mean * mean;
  float rstd = rsqrtf(var + 1e-5f);
  f32x4 gv = *(const f32x4*)&g[lane * 4];
  f32x4 bv = *(const f32x4*)&be[lane * 4];
  float y0 = (v[0]-mean)*rstd*gv[0] + bv[0];
  float y1 = (v[1]-mean)*rstd*gv[1] + bv[1];
  float y2 = (v[2]-mean)*rstd*gv[2] + bv[2];
  float y3 = (v[3]-mean)*rstd*gv[3] + bv[3];
  uint32_t lo = f2b(y0) | ((uint32_t)f2b(y1) << 16);
  uint32_t hi = f2b(y2) | ((uint32_t)f2b(y3) << 16);
  *(uint2*)&out[(size_t)token * CC + lane * 4] = make_uint2(lo, hi);
}

// ---------------- GEMM: C = A(MxK,bf16) * BT(NxK,bf16)^T + bias, epilogue variants
// BK=64: halves barrier-drain count per MFMA vs BK=32 (K is short: 256/1024).
#define BM 128
#define BN 128
#define BK 64
enum { EPI_QKV = 0, EPI_PROJ = 1, EPI_GELU = 2, EPI_FC2 = 3 };

template<int EPI>
__global__ __launch_bounds__(256)
void gemm_k(const u16* __restrict__ A, const u16* __restrict__ BT,
            const float* __restrict__ bias, int K,
            void* __restrict__ p0, const void* __restrict__ p1) {
  __shared__ u16 aL[BM * BK];
  __shared__ u16 bL[BN * BK];
  const int tid = threadIdx.x;
  const int lane = tid & 63;
  const int wv = tid >> 6;
  const int wm = wv >> 1, wn = wv & 1;

  // T1: XCD-aware block swizzle, bijective for any nwg (m204 / ERRATA #11)
  int bx = blockIdx.x, by = blockIdx.y;
  {
    int nwg = gridDim.x * gridDim.y;
    int lin = by * gridDim.x + bx;
    int q = nwg >> 3, r = nwg & 7;
    int xcd = lin & 7, idx = lin >> 3;
    int wg = (xcd < r ? xcd * (q + 1) : r * (q + 1) + (xcd - r) * q) + idx;
    bx = wg % gridDim.x;
    by = wg / gridDim.x;
  }
  const long m0 = (long)by * BM;
  const int n0 = bx * BN;

  f32x4 acc[4][4] = {};

  const int r15 = lane & 15;
  const int g4 = lane >> 4;

  // staging: row = slot>>3, 16B-chunk c8 = slot&7; LDS linear, SOURCE pre-swizzled
  // with cs = c8 ^ (row&7); read side uses ch = (kk*4+g4) ^ (row&7)  (same involution)
  for (int kt = 0; kt < K; kt += BK) {
#pragma unroll
    for (int it = 0; it < 4; ++it) {
      int slot = tid + 256 * it;
      int row = slot >> 3, c8 = slot & 7;
      int cs = c8 ^ (row & 7);
      gload_lds16(&A[(m0 + row) * K + kt + cs * 8], &aL[slot * 8]);
    }
#pragma unroll
    for (int it = 0; it < 4; ++it) {
      int slot = tid + 256 * it;
      int row = slot >> 3, c8 = slot & 7;
      int cs = c8 ^ (row & 7);
      gload_lds16(&BT[(size_t)(n0 + row) * K + kt + cs * 8], &bL[slot * 8]);
    }
    __syncthreads();   // compiler drains vmcnt before s_barrier
#pragma unroll
    for (int kk = 0; kk < 2; ++kk) {
      bf16x8 af[4], bfr[4];
#pragma unroll
      for (int m = 0; m < 4; ++m) {
        int row = wm * 64 + m * 16 + r15;
        int ch = (kk * 4 + g4) ^ (row & 7);
        af[m] = *(const bf16x8*)&aL[row * BK + ch * 8];
      }
#pragma unroll
      for (int n = 0; n < 4; ++n) {
        int row = wn * 64 + n * 16 + r15;
        int ch = (kk * 4 + g4) ^ (row & 7);
        bfr[n] = *(const bf16x8*)&bL[row * BK + ch * 8];
      }
#pragma unroll
      for (int m = 0; m < 4; ++m)
#pragma unroll
        for (int n = 0; n < 4; ++n)
          acc[m][n] = __builtin_amdgcn_mfma_f32_16x16x32_bf16(af[m], bfr[n], acc[m][n], 0, 0, 0);
    }
    __syncthreads();
  }

  // epilogue: C/D layout col = lane&15, row = (lane>>4)*4 + j
#pragma unroll
  for (int m = 0; m < 4; ++m) {
    int rb = wm * 64 + m * 16 + (lane >> 4) * 4;
#pragma unroll
    for (int n = 0; n < 4; ++n) {
      int col = n0 + wn * 64 + n * 16 + (lane & 15);
      float bv = bias[col];
#pragma unroll
      for (int j = 0; j < 4; ++j) {
        int grow = (int)m0 + rb + j;
        float v = acc[m][n][j] + bv;
        if (EPI == EPI_QKV) {
          v = fmaxf(v, 0.f);
          int s = col >> 8, head = (col >> 5) & 7, d = col & 31;
          if (s == 0) v *= ATT_SCALE;   // fold softmax scale into q
          int win = grow / 49, nn = grow % 49;
          u16* dst = (u16*)p0 + (size_t)s * ((size_t)NTOK * CC);
          dst[(((size_t)(win * NHEAD + head)) * NWT + nn) * HDIM + d] = f2b(v);
        } else if (EPI == EPI_PROJ) {
          int win = grow / 49, nn = grow % 49;
          int b = win >> 6, wh = (win >> 3) & 7, ww = win & 7;
          int i = nn / 7, jj = nn % 7;
          int h = wh * 7 + i + 3; if (h >= 56) h -= 56;
          int w = ww * 7 + jj + 3; if (w >= 56) w -= 56;
          size_t pix = (size_t)((b * 56 + h) * 56 + w);
          float o = ((const float*)p1)[pix * CC + col] + v;
          ((float*)p0)[pix * CC + col] = o;
        } else if (EPI == EPI_GELU) {
          float gl = 0.5f * v * (1.f + erff(v * 0.70710678118654752f));
          ((u16*)p0)[(size_t)grow * MLPD + col] = f2b(gl);
        } else {  // EPI_FC2
          float o = ((const float*)p1)[(size_t)grow * CC + col] + v;
          ((float*)p0)[(size_t)grow * CC + col] = o;
        }
      }
    }
  }
}

// ---------------- MFMA window attention: 1 wave = 1 (window, head), 4 waves/block
__global__ __launch_bounds__(256)
void attn_mfma_k(const u16* __restrict__ q, const u16* __restrict__ k2,
                 const u16* __restrict__ v2, const float* __restrict__ lut,
                 u16* __restrict__ out) {
  __shared__ u16 P_lds[4][64 * 72];
  const int tid = threadIdx.x;
  const int wv = tid >> 6;
  const int lane = tid & 63;
  const int c = lane & 15;
  const int g = lane >> 4;
  const int blk = blockIdx.x * 4 + wv;   // (window, head) id
  const int head = blk & 7;
  const int win = blk >> 3;
  const int wimg = win & 63;
  const int wh = wimg >> 3, ww = wimg & 7;
  const size_t base = (size_t)blk * (NWT * HDIM);
  u16* Pw = P_lds[wv];

  bf16x8 kf[4], qf[4];
#pragma unroll
  for (int t = 0; t < 4; ++t) {
    kf[t] = *(const bf16x8*)&k2[base + (size_t)(t * 16 + c) * HDIM + g * 8];
    qf[t] = *(const bf16x8*)&q [base + (size_t)(t * 16 + c) * HDIM + g * 8];
  }
  bf16x8 vf[2][2];
#pragma unroll
  for (int kcc = 0; kcc < 2; ++kcc)
#pragma unroll
    for (int td = 0; td < 2; ++td)
#pragma unroll
      for (int jj = 0; jj < 8; ++jj) {
        int m = kcc * 32 + g * 8 + jj;
        m = m < 49 ? m : 48;
        vf[kcc][td][jj] = (short)v2[base + (size_t)m * HDIM + td * 16 + c];
      }

  f32x4 acc[4][4] = {};
#pragma unroll
  for (int tm = 0; tm < 4; ++tm)
#pragma unroll
    for (int tn = 0; tn < 4; ++tn)
      acc[tm][tn] = __builtin_amdgcn_mfma_f32_16x16x32_bf16(kf[tm], qf[tn], acc[tm][tn], 0, 0, 0);

  const float* lrow = &lut[(size_t)head * 64 * 64];
  int Ln[4];
#pragma unroll
  for (int tn = 0; tn < 4; ++tn) {
    int n = tn * 16 + c;
    int i1 = (n * 9363) >> 16;
    int j1 = n - i1 * 7;
    int rh = (wh < 7) ? 0 : (i1 < 4 ? 1 : 2);
    int rw = (ww < 7) ? 0 : (j1 < 4 ? 1 : 2);
    Ln[tn] = rh * 3 + rw;
  }
  float colmax[4] = {0.f, 0.f, 0.f, 0.f};
#pragma unroll
  for (int tm = 0; tm < 4; ++tm)
#pragma unroll
    for (int j = 0; j < 4; ++j) {
      int m = tm * 16 + g * 4 + j;
      int i2 = (m * 9363) >> 16;
      int j2 = m - i2 * 7;
      int rh = (wh < 7) ? 0 : (i2 < 4 ? 1 : 2);
      int rw = (ww < 7) ? 0 : (j2 < 4 ? 1 : 2);
      int Lm = rh * 3 + rw;
#pragma unroll
      for (int tn = 0; tn < 4; ++tn) {
        float s = acc[tm][tn][j] + lrow[m * 64 + tn * 16 + c];
        s = fmaxf(s, 0.f);
        if (Lm != Ln[tn]) s = 0.f;
        acc[tm][tn][j] = s;
        colmax[tn] = fmaxf(colmax[tn], s);
      }
    }
#pragma unroll
  for (int tn = 0; tn < 4; ++tn) {
    colmax[tn] = fmaxf(colmax[tn], __shfl_xor(colmax[tn], 16));
    colmax[tn] = fmaxf(colmax[tn], __shfl_xor(colmax[tn], 32));
  }
  float colsum[4] = {0.f, 0.f, 0.f, 0.f};
#pragma unroll
  for (int tm = 0; tm < 4; ++tm)
#pragma unroll
    for (int j = 0; j < 4; ++j) {
      int m = tm * 16 + g * 4 + j;
      bool mvalid = (m < NWT);
#pragma unroll
      for (int tn = 0; tn < 4; ++tn) {
        float e = mvalid ? __expf(acc[tm][tn][j] - colmax[tn]) : 0.f;
        acc[tm][tn][j] = e;
        colsum[tn] += e;
      }
    }
#pragma unroll
  for (int tn = 0; tn < 4; ++tn) {
    colsum[tn] += __shfl_xor(colsum[tn], 16);
    colsum[tn] += __shfl_xor(colsum[tn], 32);
    colsum[tn] = 1.f / colsum[tn];
  }

#pragma unroll
  for (int tn = 0; tn < 4; ++tn) {
    int n = tn * 16 + c;
#pragma unroll
    for (int tm = 0; tm < 4; ++tm) {
      float r = colsum[tn];
      uint32_t w0 = (uint32_t)f2b(acc[tm][tn][0] * r) | ((uint32_t)f2b(acc[tm][tn][1] * r) << 16);
      uint32_t w1 = (uint32_t)f2b(acc[tm][tn][2] * r) | ((uint32_t)f2b(acc[tm][tn][3] * r) << 16);
      *(uint2*)&Pw[n * 72 + tm * 16 + g * 4] = make_uint2(w0, w1);
    }
  }

  f32x4 oacc[4][2] = {};
#pragma unroll
  for (int kcc = 0; kcc < 2; ++kcc) {
    bf16x8 pf[4];
#pragma unroll
    for (int tr = 0; tr < 4; ++tr)
      pf[tr] = *(const bf16x8*)&Pw[(tr * 16 + c) * 72 + kcc * 32 + g * 8];
#pragma unroll
    for (int tr = 0; tr < 4; ++tr)
#pragma unroll
      for (int td = 0; td < 2; ++td)
        oacc[tr][td] = __builtin_amdgcn_mfma_f32_16x16x32_bf16(pf[tr], vf[kcc][td], oacc[tr][td], 0, 0, 0);
  }

#pragma unroll
  for (int tr = 0; tr < 4; ++tr)
#pragma unroll
    for (int j = 0; j < 4; ++j) {
      int n = tr * 16 + g * 4 + j;
      if (n < NWT) {
#pragma unroll
        for (int td = 0; td < 2; ++td) {
          int d = td * 16 + c;
          out[((size_t)(win * NWT + n)) * CC + head * HDIM + d] =
              f2b(fmaxf(oacc[tr][td][j], 0.f));
        }
      }
    }
}

// ---------------- launch
extern "C" void kernel_launch(void* const* d_in, const int* in_sizes, int n_in,
                              void* d_out, int out_size, void* d_ws, size_t ws_size,
                              hipStream_t stream) {
  const float* x      = (const float*)d_in[0];
  const float* gamma1 = (const float*)d_in[1];
  const float* beta1  = (const float*)d_in[2];
  const float* w_qkv  = (const float*)d_in[3];
  const float* b_qkv  = (const float*)d_in[4];
  const float* rpb    = (const float*)d_in[5];
  const float* w_proj = (const float*)d_in[6];
  const float* b_proj = (const float*)d_in[7];
  const float* gamma2 = (const float*)d_in[8];
  const float* beta2  = (const float*)d_in[9];
  const float* w_fc1  = (const float*)d_in[10];
  const float* b_fc1  = (const float*)d_in[11];
  const float* w_fc2  = (const float*)d_in[12];
  const float* b_fc2  = (const float*)d_in[13];
  float* out = (float*)d_out;

  char* ws = (char*)d_ws;
  size_t off = 0;
  auto alloc = [&](size_t bytes) { void* p = ws + off; off = (off + bytes + 255) & ~(size_t)255; return p; };

  u16* wqkvT = (u16*)alloc(768 * 256 * 2);
  u16* wprojT = (u16*)alloc(256 * 256 * 2);
  u16* wfc1T = (u16*)alloc(1024 * 256 * 2);
  u16* wfc2T = (u16*)alloc(256 * 1024 * 2);
  float* lut = (float*)alloc(8 * 64 * 64 * 4);
  // region2: xw -> attn_out -> xn2 (lifetimes disjoint)
  u16* region2 = (u16*)alloc((size_t)NTOK * CC * 2);
  // region1: q|k|v (3x 51.4MB); after attention reused as x2 (fp32, 102.8MB) + h chunk
  char* region1 = (char*)alloc((size_t)3 * NTOK * CC * 2);

  u16* xw = region2;
  u16* qb = (u16*)region1;
  u16* kb = qb + (size_t)NTOK * CC;
  u16* vb = kb + (size_t)NTOK * CC;
  u16* attn_out = region2;
  float* x2 = (float*)region1;
  u16* xn2 = region2;
  u16* hbuf = (u16*)(region1 + (size_t)NTOK * CC * 4);  // after x2's 102.8MB

  if (ws_size < off) return;  // insufficient scratch: fail visibly

  wconv_k<<<(256 * 768 + 255) / 256, 256, 0, stream>>>(w_qkv, wqkvT, 256, 768);
  wconv_k<<<(256 * 256 + 255) / 256, 256, 0, stream>>>(w_proj, wprojT, 256, 256);
  wconv_k<<<(256 * 1024 + 255) / 256, 256, 0, stream>>>(w_fc1, wfc1T, 256, 1024);
  wconv_k<<<(1024 * 256 + 255) / 256, 256, 0, stream>>>(w_fc2, wfc2T, 1024, 256);
  bias_lut_k<<<(8 * 64 * 64) / 256, 256, 0, stream>>>(rpb, lut);

  // LN1 + shift + partition
  ln_k<true><<<NTOK / 4, 256, 0, stream>>>(x, gamma1, beta1, xw);

  // QKV GEMM: M=100352, N=768, K=256 (XCD-swizzled)
  gemm_k<EPI_QKV><<<dim3(768 / BN, NTOK / BM), 256, 0, stream>>>(
      xw, wqkvT, b_qkv, 256, (void*)qb, nullptr);

  // fused MFMA window attention: 1 wave per (window, head)
  attn_mfma_k<<<NWIN * NHEAD / 4, 256, 0, stream>>>(qb, kb, vb, lut, attn_out);

  // proj GEMM + reverse shift + residual: M=100352, N=256, K=256
  gemm_k<EPI_PROJ><<<dim3(256 / BN, NTOK / BM), 256, 0, stream>>>(
      attn_out, wprojT, b_proj, 256, (void*)x2, (const void*)x);

  // LN2
  ln_k<false><<<NTOK / 4, 256, 0, stream>>>(x2, gamma2, beta2, xn2);

  // MLP in 8 M-chunks of 12544 rows (h buffer 25.7MB) — known-good structure
  const int MCH = 12544;
  for (int c = 0; c < 8; ++c) {
    const u16* a1 = xn2 + (size_t)c * MCH * CC;
    gemm_k<EPI_GELU><<<dim3(MLPD / BN, MCH / BM), 256, 0, stream>>>(
        a1, wfc1T, b_fc1, 256, (void*)hbuf, nullptr);
    gemm_k<EPI_FC2><<<dim3(CC / BN, MCH / BM), 256, 0, stream>>>(
        hbuf, wfc2T, b_fc2, 1024, (void*)(out + (size_t)c * MCH * CC),
        (const void*)(x2 + (size_t)c * MCH * CC));
  }
}

// Round 6
// 551.506 us; speedup vs baseline: 1.5465x; 1.1771x over previous
//
#include <hip/hip_runtime.h>
#include <stdint.h>

typedef unsigned short u16;
typedef short bf16x8 __attribute__((ext_vector_type(8)));
typedef float f32x4 __attribute__((ext_vector_type(4)));

#define NTOK 100352      // B*H*W tokens
#define NWIN 2048        // B * 64 windows
#define CC 256
#define NHEAD 8
#define HDIM 32
#define NWT 49           // tokens per window
#define MLPD 1024
#define ATT_SCALE 0.17677669529663687f  // 32^-0.5

__device__ __forceinline__ u16 f2b(float f) {
  union { float f; uint32_t u; } c; c.f = f;
  return (u16)((c.u + 0x7fffu + ((c.u >> 16) & 1u)) >> 16);
}
__device__ __forceinline__ float b2f(u16 h) {
  union { uint32_t u; float f; } c; c.u = ((uint32_t)h) << 16;
  return c.f;
}

__device__ __forceinline__ void gload_lds16(const void* g, void* l) {
  __builtin_amdgcn_global_load_lds((const __attribute__((address_space(1))) void*)g,
                                   (__attribute__((address_space(3))) void*)l, 16, 0, 0);
}

// ---------------- weight convert + transpose: w[K][N] fp32 -> wT[N][K] bf16
__global__ __launch_bounds__(256) void wconv_k(const float* __restrict__ w,
                                               u16* __restrict__ wT, int K, int N) {
  int i = blockIdx.x * 256 + threadIdx.x;
  if (i < K * N) {
    int k = i / N, n = i % N;
    wT[(size_t)n * K + k] = f2b(w[i]);
  }
}

// ---------------- relative-position bias LUT: lut[h][m][n] (64x64 padded, 0 outside 49)
__global__ __launch_bounds__(256) void bias_lut_k(const float* __restrict__ rpb,
                                                  float* __restrict__ lut) {
  int i = blockIdx.x * 256 + threadIdx.x;
  if (i >= 8 * 64 * 64) return;
  int h = i >> 12, m = (i >> 6) & 63, n = i & 63;
  float v = 0.f;
  if (m < 49 && n < 49) {
    int i1 = n / 7, j1 = n % 7;   // query coords
    int i2 = m / 7, j2 = m % 7;   // key coords
    v = rpb[((i1 - i2 + 6) * 13 + (j1 - j2 + 6)) * 8 + h];
  }
  lut[i] = v;
}

// ---------------- LN (+ optional shift/window-partition) -> bf16 tokens
template<bool PART>
__global__ __launch_bounds__(256)
void ln_k(const float* __restrict__ x, const float* __restrict__ g,
          const float* __restrict__ be, u16* __restrict__ out) {
  int token = blockIdx.x * 4 + (threadIdx.x >> 6);
  int lane = threadIdx.x & 63;
  size_t src;
  if (PART) {
    int win = token / 49, nn = token % 49;
    int b = win >> 6, wh = (win >> 3) & 7, ww = win & 7;
    int i = nn / 7, j = nn % 7;
    int h = wh * 7 + i + 3; if (h >= 56) h -= 56;
    int w = ww * 7 + j + 3; if (w >= 56) w -= 56;
    src = ((size_t)((b * 56 + h) * 56 + w)) * CC;
  } else {
    src = (size_t)token * CC;
  }
  f32x4 v = *(const f32x4*)&x[src + lane * 4];
  float s1 = v[0] + v[1] + v[2] + v[3];
  float s2 = v[0]*v[0] + v[1]*v[1] + v[2]*v[2] + v[3]*v[3];
#pragma unroll
  for (int o = 32; o; o >>= 1) { s1 += __shfl_xor(s1, o); s2 += __shfl_xor(s2, o); }
  float mean = s1 * (1.f / 256.f);
  float var = s2 * (1.f / 256.f) - mean * mean;
  float rstd = rsqrtf(var + 1e-5f);
  f32x4 gv = *(const f32x4*)&g[lane * 4];
  f32x4 bv = *(const f32x4*)&be[lane * 4];
  float y0 = (v[0]-mean)*rstd*gv[0] + bv[0];
  float y1 = (v[1]-mean)*rstd*gv[1] + bv[1];
  float y2 = (v[2]-mean)*rstd*gv[2] + bv[2];
  float y3 = (v[3]-mean)*rstd*gv[3] + bv[3];
  uint32_t lo = f2b(y0) | ((uint32_t)f2b(y1) << 16);
  uint32_t hi = f2b(y2) | ((uint32_t)f2b(y3) << 16);
  *(uint2*)&out[(size_t)token * CC + lane * 4] = make_uint2(lo, hi);
}

// ---------------- GEMM v3: double-buffered LDS + prefetch-next-tile (T3 2-phase
// minimum) + hoisted addressing. BK=64, one barrier per K-tile.
#define BM 128
#define BN 128
#define BK 64
enum { EPI_QKV = 0, EPI_PROJ = 1, EPI_GELU = 2, EPI_FC2 = 3 };

template<int EPI>
__global__ __launch_bounds__(256)
void gemm_k(const u16* __restrict__ A, const u16* __restrict__ BT,
            const float* __restrict__ bias, int K,
            void* __restrict__ p0, const void* __restrict__ p1) {
  __shared__ u16 aL[2][BM * BK];
  __shared__ u16 bL[2][BN * BK];
  const int tid = threadIdx.x;
  const int lane = tid & 63;
  const int wv = tid >> 6;
  const int wm = wv >> 1, wn = wv & 1;

  // T1: XCD-aware block swizzle, bijective for any nwg (m204 / ERRATA #11)
  int bx = blockIdx.x, by = blockIdx.y;
  {
    int nwg = gridDim.x * gridDim.y;
    int lin = by * gridDim.x + bx;
    int q = nwg >> 3, r = nwg & 7;
    int xcd = lin & 7, idx = lin >> 3;
    int wg = (xcd < r ? xcd * (q + 1) : r * (q + 1) + (xcd - r) * q) + idx;
    bx = wg % gridDim.x;
    by = wg / gridDim.x;
  }
  const long m0 = (long)by * BM;
  const int n0 = bx * BN;

  f32x4 acc[4][4] = {};
  const int r15 = lane & 15;
  const int g4 = lane >> 4;

  // hoisted staging addresses (row = slot>>3, chunk c8 = slot&7; LDS linear,
  // SOURCE pre-swizzled cs = c8 ^ (row&7)); pointers advance by BK per tile
  const u16* pA[4];
  const u16* pB[4];
  int lslot[4];
#pragma unroll
  for (int it = 0; it < 4; ++it) {
    int slot = tid + 256 * it;
    int row = slot >> 3, c8 = slot & 7;
    int cs = c8 ^ (row & 7);
    pA[it] = &A[(m0 + row) * K + cs * 8];
    pB[it] = &BT[(size_t)(n0 + row) * K + cs * 8];
    lslot[it] = slot * 8;
  }
  // hoisted ds_read byte-offsets (kt-invariant), read swizzle = same involution
  int aoff[2][4], boff[2][4];
#pragma unroll
  for (int kk = 0; kk < 2; ++kk)
#pragma unroll
    for (int m = 0; m < 4; ++m) {
      int rowa = wm * 64 + m * 16 + r15;
      aoff[kk][m] = rowa * BK + (((kk * 4 + g4) ^ (rowa & 7)) << 3);
      int rowb = wn * 64 + m * 16 + r15;
      boff[kk][m] = rowb * BK + (((kk * 4 + g4) ^ (rowb & 7)) << 3);
    }

  // prologue: stage tile 0 into buf 0
#pragma unroll
  for (int it = 0; it < 4; ++it) { gload_lds16(pA[it], &aL[0][lslot[it]]); pA[it] += BK; }
#pragma unroll
  for (int it = 0; it < 4; ++it) { gload_lds16(pB[it], &bL[0][lslot[it]]); pB[it] += BK; }
  __syncthreads();

  const int nkt = K >> 6;
  int cur = 0;
  for (int kt = 0; kt < nkt; ++kt) {
    if (kt + 1 < nkt) {   // prefetch next tile into the other buffer
#pragma unroll
      for (int it = 0; it < 4; ++it) { gload_lds16(pA[it], &aL[cur ^ 1][lslot[it]]); pA[it] += BK; }
#pragma unroll
      for (int it = 0; it < 4; ++it) { gload_lds16(pB[it], &bL[cur ^ 1][lslot[it]]); pB[it] += BK; }
    }
    const u16* ab = aL[cur];
    const u16* bb = bL[cur];
#pragma unroll
    for (int kk = 0; kk < 2; ++kk) {
      bf16x8 af[4], bfr[4];
#pragma unroll
      for (int m = 0; m < 4; ++m) af[m] = *(const bf16x8*)&ab[aoff[kk][m]];
#pragma unroll
      for (int n = 0; n < 4; ++n) bfr[n] = *(const bf16x8*)&bb[boff[kk][n]];
#pragma unroll
      for (int m = 0; m < 4; ++m)
#pragma unroll
        for (int n = 0; n < 4; ++n)
          acc[m][n] = __builtin_amdgcn_mfma_f32_16x16x32_bf16(af[m], bfr[n], acc[m][n], 0, 0, 0);
    }
    __syncthreads();   // drains this iter's prefetch + fences buf reuse
    cur ^= 1;
  }

  // epilogue: C/D layout col = lane&15, row = (lane>>4)*4 + j
#pragma unroll
  for (int m = 0; m < 4; ++m) {
    int rb = wm * 64 + m * 16 + (lane >> 4) * 4;
#pragma unroll
    for (int n = 0; n < 4; ++n) {
      int col = n0 + wn * 64 + n * 16 + (lane & 15);
      float bv = bias[col];
#pragma unroll
      for (int j = 0; j < 4; ++j) {
        int grow = (int)m0 + rb + j;
        float v = acc[m][n][j] + bv;
        if (EPI == EPI_QKV) {
          v = fmaxf(v, 0.f);
          int s = col >> 8, head = (col >> 5) & 7, d = col & 31;
          if (s == 0) v *= ATT_SCALE;   // fold softmax scale into q
          int win = grow / 49, nn = grow % 49;
          u16* dst = (u16*)p0 + (size_t)s * ((size_t)NTOK * CC);
          dst[(((size_t)(win * NHEAD + head)) * NWT + nn) * HDIM + d] = f2b(v);
        } else if (EPI == EPI_PROJ) {
          int win = grow / 49, nn = grow % 49;
          int b = win >> 6, wh = (win >> 3) & 7, ww = win & 7;
          int i = nn / 7, jj = nn % 7;
          int h = wh * 7 + i + 3; if (h >= 56) h -= 56;
          int w = ww * 7 + jj + 3; if (w >= 56) w -= 56;
          size_t pix = (size_t)((b * 56 + h) * 56 + w);
          float o = ((const float*)p1)[pix * CC + col] + v;
          ((float*)p0)[pix * CC + col] = o;
        } else if (EPI == EPI_GELU) {
          float gl = 0.5f * v * (1.f + erff(v * 0.70710678118654752f));
          ((u16*)p0)[(size_t)grow * MLPD + col] = f2b(gl);
        } else {  // EPI_FC2
          float o = ((const float*)p1)[(size_t)grow * CC + col] + v;
          ((float*)p0)[(size_t)grow * CC + col] = o;
        }
      }
    }
  }
}

// ---------------- MFMA window attention: 1 wave = 1 (window, head), 4 waves/block
__global__ __launch_bounds__(256)
void attn_mfma_k(const u16* __restrict__ q, const u16* __restrict__ k2,
                 const u16* __restrict__ v2, const float* __restrict__ lut,
                 u16* __restrict__ out) {
  __shared__ u16 P_lds[4][64 * 72];
  const int tid = threadIdx.x;
  const int wv = tid >> 6;
  const int lane = tid & 63;
  const int c = lane & 15;
  const int g = lane >> 4;
  const int blk = blockIdx.x * 4 + wv;   // (window, head) id
  const int head = blk & 7;
  const int win = blk >> 3;
  const int wimg = win & 63;
  const int wh = wimg >> 3, ww = wimg & 7;
  const size_t base = (size_t)blk * (NWT * HDIM);
  u16* Pw = P_lds[wv];

  bf16x8 kf[4], qf[4];
#pragma unroll
  for (int t = 0; t < 4; ++t) {
    kf[t] = *(const bf16x8*)&k2[base + (size_t)(t * 16 + c) * HDIM + g * 8];
    qf[t] = *(const bf16x8*)&q [base + (size_t)(t * 16 + c) * HDIM + g * 8];
  }
  bf16x8 vf[2][2];
#pragma unroll
  for (int kcc = 0; kcc < 2; ++kcc)
#pragma unroll
    for (int td = 0; td < 2; ++td)
#pragma unroll
      for (int jj = 0; jj < 8; ++jj) {
        int m = kcc * 32 + g * 8 + jj;
        m = m < 49 ? m : 48;
        vf[kcc][td][jj] = (short)v2[base + (size_t)m * HDIM + td * 16 + c];
      }

  f32x4 acc[4][4] = {};
#pragma unroll
  for (int tm = 0; tm < 4; ++tm)
#pragma unroll
    for (int tn = 0; tn < 4; ++tn)
      acc[tm][tn] = __builtin_amdgcn_mfma_f32_16x16x32_bf16(kf[tm], qf[tn], acc[tm][tn], 0, 0, 0);

  const float* lrow = &lut[(size_t)head * 64 * 64];
  int Ln[4];
#pragma unroll
  for (int tn = 0; tn < 4; ++tn) {
    int n = tn * 16 + c;
    int i1 = (n * 9363) >> 16;
    int j1 = n - i1 * 7;
    int rh = (wh < 7) ? 0 : (i1 < 4 ? 1 : 2);
    int rw = (ww < 7) ? 0 : (j1 < 4 ? 1 : 2);
    Ln[tn] = rh * 3 + rw;
  }
  float colmax[4] = {0.f, 0.f, 0.f, 0.f};
#pragma unroll
  for (int tm = 0; tm < 4; ++tm)
#pragma unroll
    for (int j = 0; j < 4; ++j) {
      int m = tm * 16 + g * 4 + j;
      int i2 = (m * 9363) >> 16;
      int j2 = m - i2 * 7;
      int rh = (wh < 7) ? 0 : (i2 < 4 ? 1 : 2);
      int rw = (ww < 7) ? 0 : (j2 < 4 ? 1 : 2);
      int Lm = rh * 3 + rw;
#pragma unroll
      for (int tn = 0; tn < 4; ++tn) {
        float s = acc[tm][tn][j] + lrow[m * 64 + tn * 16 + c];
        s = fmaxf(s, 0.f);
        if (Lm != Ln[tn]) s = 0.f;
        acc[tm][tn][j] = s;
        colmax[tn] = fmaxf(colmax[tn], s);
      }
    }
#pragma unroll
  for (int tn = 0; tn < 4; ++tn) {
    colmax[tn] = fmaxf(colmax[tn], __shfl_xor(colmax[tn], 16));
    colmax[tn] = fmaxf(colmax[tn], __shfl_xor(colmax[tn], 32));
  }
  float colsum[4] = {0.f, 0.f, 0.f, 0.f};
#pragma unroll
  for (int tm = 0; tm < 4; ++tm)
#pragma unroll
    for (int j = 0; j < 4; ++j) {
      int m = tm * 16 + g * 4 + j;
      bool mvalid = (m < NWT);
#pragma unroll
      for (int tn = 0; tn < 4; ++tn) {
        float e = mvalid ? __expf(acc[tm][tn][j] - colmax[tn]) : 0.f;
        acc[tm][tn][j] = e;
        colsum[tn] += e;
      }
    }
#pragma unroll
  for (int tn = 0; tn < 4; ++tn) {
    colsum[tn] += __shfl_xor(colsum[tn], 16);
    colsum[tn] += __shfl_xor(colsum[tn], 32);
    colsum[tn] = 1.f / colsum[tn];
  }

#pragma unroll
  for (int tn = 0; tn < 4; ++tn) {
    int n = tn * 16 + c;
#pragma unroll
    for (int tm = 0; tm < 4; ++tm) {
      float r = colsum[tn];
      uint32_t w0 = (uint32_t)f2b(acc[tm][tn][0] * r) | ((uint32_t)f2b(acc[tm][tn][1] * r) << 16);
      uint32_t w1 = (uint32_t)f2b(acc[tm][tn][2] * r) | ((uint32_t)f2b(acc[tm][tn][3] * r) << 16);
      *(uint2*)&Pw[n * 72 + tm * 16 + g * 4] = make_uint2(w0, w1);
    }
  }

  f32x4 oacc[4][2] = {};
#pragma unroll
  for (int kcc = 0; kcc < 2; ++kcc) {
    bf16x8 pf[4];
#pragma unroll
    for (int tr = 0; tr < 4; ++tr)
      pf[tr] = *(const bf16x8*)&Pw[(tr * 16 + c) * 72 + kcc * 32 + g * 8];
#pragma unroll
    for (int tr = 0; tr < 4; ++tr)
#pragma unroll
      for (int td = 0; td < 2; ++td)
        oacc[tr][td] = __builtin_amdgcn_mfma_f32_16x16x32_bf16(pf[tr], vf[kcc][td], oacc[tr][td], 0, 0, 0);
  }

#pragma unroll
  for (int tr = 0; tr < 4; ++tr)
#pragma unroll
    for (int j = 0; j < 4; ++j) {
      int n = tr * 16 + g * 4 + j;
      if (n < NWT) {
#pragma unroll
        for (int td = 0; td < 2; ++td) {
          int d = td * 16 + c;
          out[((size_t)(win * NWT + n)) * CC + head * HDIM + d] =
              f2b(fmaxf(oacc[tr][td][j], 0.f));
        }
      }
    }
}

// ---------------- launch
extern "C" void kernel_launch(void* const* d_in, const int* in_sizes, int n_in,
                              void* d_out, int out_size, void* d_ws, size_t ws_size,
                              hipStream_t stream) {
  const float* x      = (const float*)d_in[0];
  const float* gamma1 = (const float*)d_in[1];
  const float* beta1  = (const float*)d_in[2];
  const float* w_qkv  = (const float*)d_in[3];
  const float* b_qkv  = (const float*)d_in[4];
  const float* rpb    = (const float*)d_in[5];
  const float* w_proj = (const float*)d_in[6];
  const float* b_proj = (const float*)d_in[7];
  const float* gamma2 = (const float*)d_in[8];
  const float* beta2  = (const float*)d_in[9];
  const float* w_fc1  = (const float*)d_in[10];
  const float* b_fc1  = (const float*)d_in[11];
  const float* w_fc2  = (const float*)d_in[12];
  const float* b_fc2  = (const float*)d_in[13];
  float* out = (float*)d_out;

  char* ws = (char*)d_ws;
  size_t off = 0;
  auto alloc = [&](size_t bytes) { void* p = ws + off; off = (off + bytes + 255) & ~(size_t)255; return p; };

  u16* wqkvT = (u16*)alloc(768 * 256 * 2);
  u16* wprojT = (u16*)alloc(256 * 256 * 2);
  u16* wfc1T = (u16*)alloc(1024 * 256 * 2);
  u16* wfc2T = (u16*)alloc(256 * 1024 * 2);
  float* lut = (float*)alloc(8 * 64 * 64 * 4);
  // region2: xw -> attn_out -> xn2 (lifetimes disjoint)
  u16* region2 = (u16*)alloc((size_t)NTOK * CC * 2);
  // region1: q|k|v (3x 51.4MB); later x2 (fp32, 102.8MB) + h chunk (51.4MB) = exact fit
  char* region1 = (char*)alloc((size_t)3 * NTOK * CC * 2);

  u16* xw = region2;
  u16* qb = (u16*)region1;
  u16* kb = qb + (size_t)NTOK * CC;
  u16* vb = kb + (size_t)NTOK * CC;
  u16* attn_out = region2;
  float* x2 = (float*)region1;
  u16* xn2 = region2;
  u16* hbuf = (u16*)(region1 + (size_t)NTOK * CC * 4);  // after x2's 102.8MB

  if (ws_size < off) return;  // insufficient scratch: fail visibly

  wconv_k<<<(256 * 768 + 255) / 256, 256, 0, stream>>>(w_qkv, wqkvT, 256, 768);
  wconv_k<<<(256 * 256 + 255) / 256, 256, 0, stream>>>(w_proj, wprojT, 256, 256);
  wconv_k<<<(256 * 1024 + 255) / 256, 256, 0, stream>>>(w_fc1, wfc1T, 256, 1024);
  wconv_k<<<(1024 * 256 + 255) / 256, 256, 0, stream>>>(w_fc2, wfc2T, 1024, 256);
  bias_lut_k<<<(8 * 64 * 64) / 256, 256, 0, stream>>>(rpb, lut);

  // LN1 + shift + partition
  ln_k<true><<<NTOK / 4, 256, 0, stream>>>(x, gamma1, beta1, xw);

  // QKV GEMM: M=100352, N=768, K=256 (XCD-swizzled, dbuf)
  gemm_k<EPI_QKV><<<dim3(768 / BN, NTOK / BM), 256, 0, stream>>>(
      xw, wqkvT, b_qkv, 256, (void*)qb, nullptr);

  // fused MFMA window attention: 1 wave per (window, head)
  attn_mfma_k<<<NWIN * NHEAD / 4, 256, 0, stream>>>(qb, kb, vb, lut, attn_out);

  // proj GEMM + reverse shift + residual: M=100352, N=256, K=256
  gemm_k<EPI_PROJ><<<dim3(256 / BN, NTOK / BM), 256, 0, stream>>>(
      attn_out, wprojT, b_proj, 256, (void*)x2, (const void*)x);

  // LN2
  ln_k<false><<<NTOK / 4, 256, 0, stream>>>(x2, gamma2, beta2, xn2);

  // MLP in 4 M-chunks of 25088 rows (h chunk 51.4MB, fits region1 tail exactly)
  const int MCH = 25088;
  for (int c = 0; c < 4; ++c) {
    const u16* a1 = xn2 + (size_t)c * MCH * CC;
    gemm_k<EPI_GELU><<<dim3(MLPD / BN, MCH / BM), 256, 0, stream>>>(
        a1, wfc1T, b_fc1, 256, (void*)hbuf, nullptr);
    gemm_k<EPI_FC2><<<dim3(CC / BN, MCH / BM), 256, 0, stream>>>(
        hbuf, wfc2T, b_fc2, 1024, (void*)(out + (size_t)c * MCH * CC),
        (const void*)(x2 + (size_t)c * MCH * CC));
  }
}

// Round 7
// 525.191 us; speedup vs baseline: 1.6240x; 1.0501x over previous
//
#include <hip/hip_runtime.h>
#include <stdint.h>

typedef unsigned short u16;
typedef short bf16x8 __attribute__((ext_vector_type(8)));
typedef float f32x4 __attribute__((ext_vector_type(4)));

#define NTOK 100352      // B*H*W tokens
#define NWIN 2048        // B * 64 windows
#define CC 256
#define NHEAD 8
#define HDIM 32
#define NWT 49           // tokens per window
#define MLPD 1024
#define ATT_SCALE 0.17677669529663687f  // 32^-0.5

__device__ __forceinline__ u16 f2b(float f) {
  union { float f; uint32_t u; } c; c.f = f;
  return (u16)((c.u + 0x7fffu + ((c.u >> 16) & 1u)) >> 16);
}
__device__ __forceinline__ float b2f(u16 h) {
  union { uint32_t u; float f; } c; c.u = ((uint32_t)h) << 16;
  return c.f;
}

__device__ __forceinline__ void gload_lds16(const void* g, void* l) {
  __builtin_amdgcn_global_load_lds((const __attribute__((address_space(1))) void*)g,
                                   (__attribute__((address_space(3))) void*)l, 16, 0, 0);
}

// ---------------- weight convert + transpose: w[K][N] fp32 -> wT[N][K] bf16
__global__ __launch_bounds__(256) void wconv_k(const float* __restrict__ w,
                                               u16* __restrict__ wT, int K, int N) {
  int i = blockIdx.x * 256 + threadIdx.x;
  if (i < K * N) {
    int k = i / N, n = i % N;
    wT[(size_t)n * K + k] = f2b(w[i]);
  }
}

// ---------------- relative-position bias LUT: lut[h][m][n] (64x64 padded, 0 outside 49)
__global__ __launch_bounds__(256) void bias_lut_k(const float* __restrict__ rpb,
                                                  float* __restrict__ lut) {
  int i = blockIdx.x * 256 + threadIdx.x;
  if (i >= 8 * 64 * 64) return;
  int h = i >> 12, m = (i >> 6) & 63, n = i & 63;
  float v = 0.f;
  if (m < 49 && n < 49) {
    int i1 = n / 7, j1 = n % 7;   // query coords
    int i2 = m / 7, j2 = m % 7;   // key coords
    v = rpb[((i1 - i2 + 6) * 13 + (j1 - j2 + 6)) * 8 + h];
  }
  lut[i] = v;
}

// ---------------- LN (+ optional shift/window-partition) -> bf16 tokens
template<bool PART>
__global__ __launch_bounds__(256)
void ln_k(const float* __restrict__ x, const float* __restrict__ g,
          const float* __restrict__ be, u16* __restrict__ out) {
  int token = blockIdx.x * 4 + (threadIdx.x >> 6);
  int lane = threadIdx.x & 63;
  size_t src;
  if (PART) {
    int win = token / 49, nn = token % 49;
    int b = win >> 6, wh = (win >> 3) & 7, ww = win & 7;
    int i = nn / 7, j = nn % 7;
    int h = wh * 7 + i + 3; if (h >= 56) h -= 56;
    int w = ww * 7 + j + 3; if (w >= 56) w -= 56;
    src = ((size_t)((b * 56 + h) * 56 + w)) * CC;
  } else {
    src = (size_t)token * CC;
  }
  f32x4 v = *(const f32x4*)&x[src + lane * 4];
  float s1 = v[0] + v[1] + v[2] + v[3];
  float s2 = v[0]*v[0] + v[1]*v[1] + v[2]*v[2] + v[3]*v[3];
#pragma unroll
  for (int o = 32; o; o >>= 1) { s1 += __shfl_xor(s1, o); s2 += __shfl_xor(s2, o); }
  float mean = s1 * (1.f / 256.f);
  float var = s2 * (1.f / 256.f) - mean * mean;
  float rstd = rsqrtf(var + 1e-5f);
  f32x4 gv = *(const f32x4*)&g[lane * 4];
  f32x4 bv = *(const f32x4*)&be[lane * 4];
  float y0 = (v[0]-mean)*rstd*gv[0] + bv[0];
  float y1 = (v[1]-mean)*rstd*gv[1] + bv[1];
  float y2 = (v[2]-mean)*rstd*gv[2] + bv[2];
  float y3 = (v[3]-mean)*rstd*gv[3] + bv[3];
  uint32_t lo = f2b(y0) | ((uint32_t)f2b(y1) << 16);
  uint32_t hi = f2b(y2) | ((uint32_t)f2b(y3) << 16);
  *(uint2*)&out[(size_t)token * CC + lane * 4] = make_uint2(lo, hi);
}

// ---------------- GEMM v4: double-buffered LDS + COUNTED vmcnt pipeline (T3+T4).
// Raw s_barrier; vmcnt(8) in steady state (stage(t+1),(t+2) stay in flight),
// vmcnt(0) only on the last tile. sched_barrier(0) fences per rule #18/m152.
#define BM 128
#define BN 128
#define BK 64
enum { EPI_QKV = 0, EPI_PROJ = 1, EPI_GELU = 2, EPI_FC2 = 3 };

template<int EPI, int NKT>
__global__ __launch_bounds__(256)
void gemm_k(const u16* __restrict__ A, const u16* __restrict__ BT,
            const float* __restrict__ bias,
            void* __restrict__ p0, const void* __restrict__ p1) {
  constexpr int K = NKT * BK;
  __shared__ u16 aL[2][BM * BK];
  __shared__ u16 bL[2][BN * BK];
  const int tid = threadIdx.x;
  const int lane = tid & 63;
  const int wv = tid >> 6;
  const int wm = wv >> 1, wn = wv & 1;

  // T1: XCD-aware block swizzle, bijective for any nwg (m204 / ERRATA #11)
  int bx = blockIdx.x, by = blockIdx.y;
  {
    int nwg = gridDim.x * gridDim.y;
    int lin = by * gridDim.x + bx;
    int q = nwg >> 3, r = nwg & 7;
    int xcd = lin & 7, idx = lin >> 3;
    int wg = (xcd < r ? xcd * (q + 1) : r * (q + 1) + (xcd - r) * q) + idx;
    bx = wg % gridDim.x;
    by = wg / gridDim.x;
  }
  const long m0 = (long)by * BM;
  const int n0 = bx * BN;

  f32x4 acc[4][4] = {};
  const int r15 = lane & 15;
  const int g4 = lane >> 4;

  // hoisted staging addresses (row = slot>>3, chunk c8 = slot&7; LDS linear,
  // SOURCE pre-swizzled cs = c8 ^ (row&7)); pointers advance by BK per tile
  const u16* pA[4];
  const u16* pB[4];
  int lslot[4];
#pragma unroll
  for (int it = 0; it < 4; ++it) {
    int slot = tid + 256 * it;
    int row = slot >> 3, c8 = slot & 7;
    int cs = c8 ^ (row & 7);
    pA[it] = &A[(m0 + row) * K + cs * 8];
    pB[it] = &BT[(size_t)(n0 + row) * K + cs * 8];
    lslot[it] = slot * 8;
  }
  // hoisted ds_read byte-offsets (kt-invariant), read swizzle = same involution
  int aoff[2][4], boff[2][4];
#pragma unroll
  for (int kk = 0; kk < 2; ++kk)
#pragma unroll
    for (int m = 0; m < 4; ++m) {
      int rowa = wm * 64 + m * 16 + r15;
      aoff[kk][m] = rowa * BK + (((kk * 4 + g4) ^ (rowa & 7)) << 3);
      int rowb = wn * 64 + m * 16 + r15;
      boff[kk][m] = rowb * BK + (((kk * 4 + g4) ^ (rowb & 7)) << 3);
    }

  auto stage = [&](int bufi) {
#pragma unroll
    for (int it = 0; it < 4; ++it) { gload_lds16(pA[it], &aL[bufi][lslot[it]]); pA[it] += BK; }
#pragma unroll
    for (int it = 0; it < 4; ++it) { gload_lds16(pB[it], &bL[bufi][lslot[it]]); pB[it] += BK; }
  };

  // prologue: issue tiles 0 and 1 (16 loads in flight, no drain)
  stage(0);
  stage(1);

#pragma unroll
  for (int t = 0; t < NKT; ++t) {
    // wait for tile t only: 8 newer loads (stage t+1 or t+2) may stay in flight
    if (t + 1 < NKT) asm volatile("s_waitcnt vmcnt(8)" ::: "memory");
    else             asm volatile("s_waitcnt vmcnt(0)" ::: "memory");
    __builtin_amdgcn_sched_barrier(0);
    __builtin_amdgcn_s_barrier();           // all waves: tile t LDS-visible
    __builtin_amdgcn_sched_barrier(0);
    {
      const u16* ab = aL[t & 1];
      const u16* bb = bL[t & 1];
#pragma unroll
      for (int kk = 0; kk < 2; ++kk) {
        bf16x8 af[4], bfr[4];
#pragma unroll
        for (int m = 0; m < 4; ++m) af[m] = *(const bf16x8*)&ab[aoff[kk][m]];
#pragma unroll
        for (int n = 0; n < 4; ++n) bfr[n] = *(const bf16x8*)&bb[boff[kk][n]];
#pragma unroll
        for (int m = 0; m < 4; ++m)
#pragma unroll
          for (int n = 0; n < 4; ++n)
            acc[m][n] = __builtin_amdgcn_mfma_f32_16x16x32_bf16(af[m], bfr[n], acc[m][n], 0, 0, 0);
      }
    }
    __builtin_amdgcn_sched_barrier(0);
    __builtin_amdgcn_s_barrier();           // all waves done reading buf[t&1]
    __builtin_amdgcn_sched_barrier(0);
    if (t + 2 < NKT) stage(t & 1);          // overwrite the just-consumed buffer
  }

  // epilogue: C/D layout col = lane&15, row = (lane>>4)*4 + j
#pragma unroll
  for (int m = 0; m < 4; ++m) {
    int rb = wm * 64 + m * 16 + (lane >> 4) * 4;
    int row0 = (int)m0 + rb;
    int winj[4], nnj[4];
    if (EPI == EPI_QKV || EPI == EPI_PROJ) {
      int w0 = row0 / 49, nr = row0 - w0 * 49;   // one div; increment for j=1..3
#pragma unroll
      for (int j = 0; j < 4; ++j) {
        winj[j] = w0; nnj[j] = nr;
        if (++nr == 49) { nr = 0; ++w0; }
      }
    }
#pragma unroll
    for (int n = 0; n < 4; ++n) {
      int col = n0 + wn * 64 + n * 16 + (lane & 15);
      float bv = bias[col];
#pragma unroll
      for (int j = 0; j < 4; ++j) {
        float v = acc[m][n][j] + bv;
        if (EPI == EPI_QKV) {
          v = fmaxf(v, 0.f);
          int s = col >> 8, head = (col >> 5) & 7, d = col & 31;
          if (s == 0) v *= ATT_SCALE;   // fold softmax scale into q
          u16* dst = (u16*)p0 + (size_t)s * ((size_t)NTOK * CC);
          dst[(((size_t)(winj[j] * NHEAD + head)) * NWT + nnj[j]) * HDIM + d] = f2b(v);
        } else if (EPI == EPI_PROJ) {
          int win = winj[j], nn = nnj[j];
          int b = win >> 6, wh = (win >> 3) & 7, ww = win & 7;
          int i = nn / 7, jj = nn % 7;
          int h = wh * 7 + i + 3; if (h >= 56) h -= 56;
          int w = ww * 7 + jj + 3; if (w >= 56) w -= 56;
          size_t pix = (size_t)((b * 56 + h) * 56 + w);
          float o = ((const float*)p1)[pix * CC + col] + v;
          ((float*)p0)[pix * CC + col] = o;
        } else if (EPI == EPI_GELU) {
          float gl = 0.5f * v * (1.f + erff(v * 0.70710678118654752f));
          ((u16*)p0)[(size_t)(row0 + j) * MLPD + col] = f2b(gl);
        } else {  // EPI_FC2
          size_t idx = (size_t)(row0 + j) * CC + col;
          float o = ((const float*)p1)[idx] + v;
          ((float*)p0)[idx] = o;
        }
      }
    }
  }
}

// ---------------- MFMA window attention: 1 wave = 1 (window, head), 4 waves/block
__global__ __launch_bounds__(256)
void attn_mfma_k(const u16* __restrict__ q, const u16* __restrict__ k2,
                 const u16* __restrict__ v2, const float* __restrict__ lut,
                 u16* __restrict__ out) {
  __shared__ u16 P_lds[4][64 * 72];
  const int tid = threadIdx.x;
  const int wv = tid >> 6;
  const int lane = tid & 63;
  const int c = lane & 15;
  const int g = lane >> 4;
  const int blk = blockIdx.x * 4 + wv;   // (window, head) id
  const int head = blk & 7;
  const int win = blk >> 3;
  const int wimg = win & 63;
  const int wh = wimg >> 3, ww = wimg & 7;
  const size_t base = (size_t)blk * (NWT * HDIM);
  u16* Pw = P_lds[wv];

  bf16x8 kf[4], qf[4];
#pragma unroll
  for (int t = 0; t < 4; ++t) {
    kf[t] = *(const bf16x8*)&k2[base + (size_t)(t * 16 + c) * HDIM + g * 8];
    qf[t] = *(const bf16x8*)&q [base + (size_t)(t * 16 + c) * HDIM + g * 8];
  }
  bf16x8 vf[2][2];
#pragma unroll
  for (int kcc = 0; kcc < 2; ++kcc)
#pragma unroll
    for (int td = 0; td < 2; ++td)
#pragma unroll
      for (int jj = 0; jj < 8; ++jj) {
        int m = kcc * 32 + g * 8 + jj;
        m = m < 49 ? m : 48;
        vf[kcc][td][jj] = (short)v2[base + (size_t)m * HDIM + td * 16 + c];
      }

  f32x4 acc[4][4] = {};
#pragma unroll
  for (int tm = 0; tm < 4; ++tm)
#pragma unroll
    for (int tn = 0; tn < 4; ++tn)
      acc[tm][tn] = __builtin_amdgcn_mfma_f32_16x16x32_bf16(kf[tm], qf[tn], acc[tm][tn], 0, 0, 0);

  const float* lrow = &lut[(size_t)head * 64 * 64];
  int Ln[4];
#pragma unroll
  for (int tn = 0; tn < 4; ++tn) {
    int n = tn * 16 + c;
    int i1 = (n * 9363) >> 16;
    int j1 = n - i1 * 7;
    int rh = (wh < 7) ? 0 : (i1 < 4 ? 1 : 2);
    int rw = (ww < 7) ? 0 : (j1 < 4 ? 1 : 2);
    Ln[tn] = rh * 3 + rw;
  }
  float colmax[4] = {0.f, 0.f, 0.f, 0.f};
#pragma unroll
  for (int tm = 0; tm < 4; ++tm)
#pragma unroll
    for (int j = 0; j < 4; ++j) {
      int m = tm * 16 + g * 4 + j;
      int i2 = (m * 9363) >> 16;
      int j2 = m - i2 * 7;
      int rh = (wh < 7) ? 0 : (i2 < 4 ? 1 : 2);
      int rw = (ww < 7) ? 0 : (j2 < 4 ? 1 : 2);
      int Lm = rh * 3 + rw;
#pragma unroll
      for (int tn = 0; tn < 4; ++tn) {
        float s = acc[tm][tn][j] + lrow[m * 64 + tn * 16 + c];
        s = fmaxf(s, 0.f);
        if (Lm != Ln[tn]) s = 0.f;
        acc[tm][tn][j] = s;
        colmax[tn] = fmaxf(colmax[tn], s);
      }
    }
#pragma unroll
  for (int tn = 0; tn < 4; ++tn) {
    colmax[tn] = fmaxf(colmax[tn], __shfl_xor(colmax[tn], 16));
    colmax[tn] = fmaxf(colmax[tn], __shfl_xor(colmax[tn], 32));
  }
  float colsum[4] = {0.f, 0.f, 0.f, 0.f};
#pragma unroll
  for (int tm = 0; tm < 4; ++tm)
#pragma unroll
    for (int j = 0; j < 4; ++j) {
      int m = tm * 16 + g * 4 + j;
      bool mvalid = (m < NWT);
#pragma unroll
      for (int tn = 0; tn < 4; ++tn) {
        float e = mvalid ? __expf(acc[tm][tn][j] - colmax[tn]) : 0.f;
        acc[tm][tn][j] = e;
        colsum[tn] += e;
      }
    }
#pragma unroll
  for (int tn = 0; tn < 4; ++tn) {
    colsum[tn] += __shfl_xor(colsum[tn], 16);
    colsum[tn] += __shfl_xor(colsum[tn], 32);
    colsum[tn] = 1.f / colsum[tn];
  }

#pragma unroll
  for (int tn = 0; tn < 4; ++tn) {
    int n = tn * 16 + c;
#pragma unroll
    for (int tm = 0; tm < 4; ++tm) {
      float r = colsum[tn];
      uint32_t w0 = (uint32_t)f2b(acc[tm][tn][0] * r) | ((uint32_t)f2b(acc[tm][tn][1] * r) << 16);
      uint32_t w1 = (uint32_t)f2b(acc[tm][tn][2] * r) | ((uint32_t)f2b(acc[tm][tn][3] * r) << 16);
      *(uint2*)&Pw[n * 72 + tm * 16 + g * 4] = make_uint2(w0, w1);
    }
  }

  f32x4 oacc[4][2] = {};
#pragma unroll
  for (int kcc = 0; kcc < 2; ++kcc) {
    bf16x8 pf[4];
#pragma unroll
    for (int tr = 0; tr < 4; ++tr)
      pf[tr] = *(const bf16x8*)&Pw[(tr * 16 + c) * 72 + kcc * 32 + g * 8];
#pragma unroll
    for (int tr = 0; tr < 4; ++tr)
#pragma unroll
      for (int td = 0; td < 2; ++td)
        oacc[tr][td] = __builtin_amdgcn_mfma_f32_16x16x32_bf16(pf[tr], vf[kcc][td], oacc[tr][td], 0, 0, 0);
  }

#pragma unroll
  for (int tr = 0; tr < 4; ++tr)
#pragma unroll
    for (int j = 0; j < 4; ++j) {
      int n = tr * 16 + g * 4 + j;
      if (n < NWT) {
#pragma unroll
        for (int td = 0; td < 2; ++td) {
          int d = td * 16 + c;
          out[((size_t)(win * NWT + n)) * CC + head * HDIM + d] =
              f2b(fmaxf(oacc[tr][td][j], 0.f));
        }
      }
    }
}

// ---------------- launch
extern "C" void kernel_launch(void* const* d_in, const int* in_sizes, int n_in,
                              void* d_out, int out_size, void* d_ws, size_t ws_size,
                              hipStream_t stream) {
  const float* x      = (const float*)d_in[0];
  const float* gamma1 = (const float*)d_in[1];
  const float* beta1  = (const float*)d_in[2];
  const float* w_qkv  = (const float*)d_in[3];
  const float* b_qkv  = (const float*)d_in[4];
  const float* rpb    = (const float*)d_in[5];
  const float* w_proj = (const float*)d_in[6];
  const float* b_proj = (const float*)d_in[7];
  const float* gamma2 = (const float*)d_in[8];
  const float* beta2  = (const float*)d_in[9];
  const float* w_fc1  = (const float*)d_in[10];
  const float* b_fc1  = (const float*)d_in[11];
  const float* w_fc2  = (const float*)d_in[12];
  const float* b_fc2  = (const float*)d_in[13];
  float* out = (float*)d_out;

  char* ws = (char*)d_ws;
  size_t off = 0;
  auto alloc = [&](size_t bytes) { void* p = ws + off; off = (off + bytes + 255) & ~(size_t)255; return p; };

  u16* wqkvT = (u16*)alloc(768 * 256 * 2);
  u16* wprojT = (u16*)alloc(256 * 256 * 2);
  u16* wfc1T = (u16*)alloc(1024 * 256 * 2);
  u16* wfc2T = (u16*)alloc(256 * 1024 * 2);
  float* lut = (float*)alloc(8 * 64 * 64 * 4);
  // region2: xw -> attn_out -> xn2 (lifetimes disjoint)
  u16* region2 = (u16*)alloc((size_t)NTOK * CC * 2);
  // region1: q|k|v (3x 51.4MB); later x2 (fp32, 102.8MB) + h chunk (51.4MB) = exact fit
  char* region1 = (char*)alloc((size_t)3 * NTOK * CC * 2);

  u16* xw = region2;
  u16* qb = (u16*)region1;
  u16* kb = qb + (size_t)NTOK * CC;
  u16* vb = kb + (size_t)NTOK * CC;
  u16* attn_out = region2;
  float* x2 = (float*)region1;
  u16* xn2 = region2;
  u16* hbuf = (u16*)(region1 + (size_t)NTOK * CC * 4);  // after x2's 102.8MB

  if (ws_size < off) return;  // insufficient scratch: fail visibly

  wconv_k<<<(256 * 768 + 255) / 256, 256, 0, stream>>>(w_qkv, wqkvT, 256, 768);
  wconv_k<<<(256 * 256 + 255) / 256, 256, 0, stream>>>(w_proj, wprojT, 256, 256);
  wconv_k<<<(256 * 1024 + 255) / 256, 256, 0, stream>>>(w_fc1, wfc1T, 256, 1024);
  wconv_k<<<(1024 * 256 + 255) / 256, 256, 0, stream>>>(w_fc2, wfc2T, 1024, 256);
  bias_lut_k<<<(8 * 64 * 64) / 256, 256, 0, stream>>>(rpb, lut);

  // LN1 + shift + partition
  ln_k<true><<<NTOK / 4, 256, 0, stream>>>(x, gamma1, beta1, xw);

  // QKV GEMM: M=100352, N=768, K=256 (counted-vmcnt pipeline)
  gemm_k<EPI_QKV, 4><<<dim3(768 / BN, NTOK / BM), 256, 0, stream>>>(
      xw, wqkvT, b_qkv, (void*)qb, nullptr);

  // fused MFMA window attention: 1 wave per (window, head)
  attn_mfma_k<<<NWIN * NHEAD / 4, 256, 0, stream>>>(qb, kb, vb, lut, attn_out);

  // proj GEMM + reverse shift + residual: M=100352, N=256, K=256
  gemm_k<EPI_PROJ, 4><<<dim3(256 / BN, NTOK / BM), 256, 0, stream>>>(
      attn_out, wprojT, b_proj, (void*)x2, (const void*)x);

  // LN2
  ln_k<false><<<NTOK / 4, 256, 0, stream>>>(x2, gamma2, beta2, xn2);

  // MLP in 4 M-chunks of 25088 rows (h chunk 51.4MB, fits region1 tail exactly)
  const int MCH = 25088;
  for (int c = 0; c < 4; ++c) {
    const u16* a1 = xn2 + (size_t)c * MCH * CC;
    gemm_k<EPI_GELU, 4><<<dim3(MLPD / BN, MCH / BM), 256, 0, stream>>>(
        a1, wfc1T, b_fc1, (void*)hbuf, nullptr);
    gemm_k<EPI_FC2, 16><<<dim3(CC / BN, MCH / BM), 256, 0, stream>>>(
        hbuf, wfc2T, b_fc2, (void*)(out + (size_t)c * MCH * CC),
        (const void*)(x2 + (size_t)c * MCH * CC));
  }
}

// Round 8
// 516.572 us; speedup vs baseline: 1.6511x; 1.0167x over previous
//
#include <hip/hip_runtime.h>
#include <stdint.h>

typedef unsigned short u16;
typedef short bf16x8 __attribute__((ext_vector_type(8)));
typedef float f32x4 __attribute__((ext_vector_type(4)));

#define NTOK 100352      // B*H*W tokens
#define NWIN 2048        // B * 64 windows
#define CC 256
#define NHEAD 8
#define HDIM 32
#define NWT 49           // tokens per window
#define MLPD 1024
#define ATT_SCALE 0.17677669529663687f  // 32^-0.5

__device__ __forceinline__ u16 f2b(float f) {
  union { float f; uint32_t u; } c; c.f = f;
  return (u16)((c.u + 0x7fffu + ((c.u >> 16) & 1u)) >> 16);
}
__device__ __forceinline__ float b2f(u16 h) {
  union { uint32_t u; float f; } c; c.u = ((uint32_t)h) << 16;
  return c.f;
}

__device__ __forceinline__ void gload_lds16(const void* g, void* l) {
  __builtin_amdgcn_global_load_lds((const __attribute__((address_space(1))) void*)g,
                                   (__attribute__((address_space(3))) void*)l, 16, 0, 0);
}

// ---------------- weight convert + transpose: w[K][N] fp32 -> wT[N][K] bf16
__global__ __launch_bounds__(256) void wconv_k(const float* __restrict__ w,
                                               u16* __restrict__ wT, int K, int N) {
  int i = blockIdx.x * 256 + threadIdx.x;
  if (i < K * N) {
    int k = i / N, n = i % N;
    wT[(size_t)n * K + k] = f2b(w[i]);
  }
}

// ---------------- relative-position bias LUT: lut[h][m][n] (64x64 padded, 0 outside 49)
__global__ __launch_bounds__(256) void bias_lut_k(const float* __restrict__ rpb,
                                                  float* __restrict__ lut) {
  int i = blockIdx.x * 256 + threadIdx.x;
  if (i >= 8 * 64 * 64) return;
  int h = i >> 12, m = (i >> 6) & 63, n = i & 63;
  float v = 0.f;
  if (m < 49 && n < 49) {
    int i1 = n / 7, j1 = n % 7;   // query coords
    int i2 = m / 7, j2 = m % 7;   // key coords
    v = rpb[((i1 - i2 + 6) * 13 + (j1 - j2 + 6)) * 8 + h];
  }
  lut[i] = v;
}

// ---------------- LN (+ optional shift/window-partition) -> bf16 tokens
template<bool PART>
__global__ __launch_bounds__(256)
void ln_k(const float* __restrict__ x, const float* __restrict__ g,
          const float* __restrict__ be, u16* __restrict__ out) {
  int token = blockIdx.x * 4 + (threadIdx.x >> 6);
  int lane = threadIdx.x & 63;
  size_t src;
  if (PART) {
    int win = token / 49, nn = token % 49;
    int b = win >> 6, wh = (win >> 3) & 7, ww = win & 7;
    int i = nn / 7, j = nn % 7;
    int h = wh * 7 + i + 3; if (h >= 56) h -= 56;
    int w = ww * 7 + j + 3; if (w >= 56) w -= 56;
    src = ((size_t)((b * 56 + h) * 56 + w)) * CC;
  } else {
    src = (size_t)token * CC;
  }
  f32x4 v = *(const f32x4*)&x[src + lane * 4];
  float s1 = v[0] + v[1] + v[2] + v[3];
  float s2 = v[0]*v[0] + v[1]*v[1] + v[2]*v[2] + v[3]*v[3];
#pragma unroll
  for (int o = 32; o; o >>= 1) { s1 += __shfl_xor(s1, o); s2 += __shfl_xor(s2, o); }
  float mean = s1 * (1.f / 256.f);
  float var = s2 * (1.f / 256.f) - mean * mean;
  float rstd = rsqrtf(var + 1e-5f);
  f32x4 gv = *(const f32x4*)&g[lane * 4];
  f32x4 bv = *(const f32x4*)&be[lane * 4];
  float y0 = (v[0]-mean)*rstd*gv[0] + bv[0];
  float y1 = (v[1]-mean)*rstd*gv[1] + bv[1];
  float y2 = (v[2]-mean)*rstd*gv[2] + bv[2];
  float y3 = (v[3]-mean)*rstd*gv[3] + bv[3];
  uint32_t lo = f2b(y0) | ((uint32_t)f2b(y1) << 16);
  uint32_t hi = f2b(y2) | ((uint32_t)f2b(y3) << 16);
  *(uint2*)&out[(size_t)token * CC + lane * 4] = make_uint2(lo, hi);
}

// ---------------- GEMM v5: counted-vmcnt pipeline + SWAPPED-OPERAND C^T epilogue.
// acc[n][m] = mfma(B_frag, A_frag, acc): lane holds one C-row (lane&15) and 4
// CONSECUTIVE C-cols ((lane>>4)*4+j) -> packed uint2/f32x4 epilogue stores.
#define BM 128
#define BN 128
#define BK 64
enum { EPI_QKV = 0, EPI_PROJ = 1, EPI_GELU = 2, EPI_FC2 = 3 };

template<int EPI, int NKT>
__global__ __launch_bounds__(256)
void gemm_k(const u16* __restrict__ A, const u16* __restrict__ BT,
            const float* __restrict__ bias,
            void* __restrict__ p0, const void* __restrict__ p1) {
  constexpr int K = NKT * BK;
  __shared__ u16 aL[2][BM * BK];
  __shared__ u16 bL[2][BN * BK];
  const int tid = threadIdx.x;
  const int lane = tid & 63;
  const int wv = tid >> 6;
  const int wm = wv >> 1, wn = wv & 1;

  // T1: XCD-aware block swizzle, bijective for any nwg (m204 / ERRATA #11)
  int bx = blockIdx.x, by = blockIdx.y;
  {
    int nwg = gridDim.x * gridDim.y;
    int lin = by * gridDim.x + bx;
    int q = nwg >> 3, r = nwg & 7;
    int xcd = lin & 7, idx = lin >> 3;
    int wg = (xcd < r ? xcd * (q + 1) : r * (q + 1) + (xcd - r) * q) + idx;
    bx = wg % gridDim.x;
    by = wg / gridDim.x;
  }
  const long m0 = (long)by * BM;
  const int n0 = bx * BN;

  f32x4 acc[4][4] = {};   // [n-tile][m-tile]
  const int r15 = lane & 15;
  const int g4 = lane >> 4;

  // hoisted staging addresses (row = slot>>3, chunk c8 = slot&7; LDS linear,
  // SOURCE pre-swizzled cs = c8 ^ (row&7)); pointers advance by BK per tile
  const u16* pA[4];
  const u16* pB[4];
  int lslot[4];
#pragma unroll
  for (int it = 0; it < 4; ++it) {
    int slot = tid + 256 * it;
    int row = slot >> 3, c8 = slot & 7;
    int cs = c8 ^ (row & 7);
    pA[it] = &A[(m0 + row) * K + cs * 8];
    pB[it] = &BT[(size_t)(n0 + row) * K + cs * 8];
    lslot[it] = slot * 8;
  }
  // hoisted ds_read byte-offsets (kt-invariant), read swizzle = same involution
  int aoff[2][4], boff[2][4];
#pragma unroll
  for (int kk = 0; kk < 2; ++kk)
#pragma unroll
    for (int m = 0; m < 4; ++m) {
      int rowa = wm * 64 + m * 16 + r15;
      aoff[kk][m] = rowa * BK + (((kk * 4 + g4) ^ (rowa & 7)) << 3);
      int rowb = wn * 64 + m * 16 + r15;
      boff[kk][m] = rowb * BK + (((kk * 4 + g4) ^ (rowb & 7)) << 3);
    }

  auto stage = [&](int bufi) {
#pragma unroll
    for (int it = 0; it < 4; ++it) { gload_lds16(pA[it], &aL[bufi][lslot[it]]); pA[it] += BK; }
#pragma unroll
    for (int it = 0; it < 4; ++it) { gload_lds16(pB[it], &bL[bufi][lslot[it]]); pB[it] += BK; }
  };

  // prologue: issue tiles 0 and 1 (16 loads in flight, no drain)
  stage(0);
  stage(1);

#pragma unroll
  for (int t = 0; t < NKT; ++t) {
    // wait for tile t only: 8 newer loads (stage t+1 or t+2) may stay in flight
    if (t + 1 < NKT) asm volatile("s_waitcnt vmcnt(8)" ::: "memory");
    else             asm volatile("s_waitcnt vmcnt(0)" ::: "memory");
    __builtin_amdgcn_sched_barrier(0);
    __builtin_amdgcn_s_barrier();           // all waves: tile t LDS-visible
    __builtin_amdgcn_sched_barrier(0);
    {
      const u16* ab = aL[t & 1];
      const u16* bb = bL[t & 1];
#pragma unroll
      for (int kk = 0; kk < 2; ++kk) {
        bf16x8 af[4], bfr[4];
#pragma unroll
        for (int m = 0; m < 4; ++m) af[m] = *(const bf16x8*)&ab[aoff[kk][m]];
#pragma unroll
        for (int n = 0; n < 4; ++n) bfr[n] = *(const bf16x8*)&bb[boff[kk][n]];
#pragma unroll
        for (int n = 0; n < 4; ++n)
#pragma unroll
          for (int m = 0; m < 4; ++m)
            acc[n][m] = __builtin_amdgcn_mfma_f32_16x16x32_bf16(bfr[n], af[m], acc[n][m], 0, 0, 0);
      }
    }
    __builtin_amdgcn_sched_barrier(0);
    __builtin_amdgcn_s_barrier();           // all waves done reading buf[t&1]
    __builtin_amdgcn_sched_barrier(0);
    if (t + 2 < NKT) stage(t & 1);          // overwrite the just-consumed buffer
  }

  // epilogue (C^T layout): lane holds C-row mrow = ..+ (lane&15) fixed,
  // and 4 consecutive C-cols col0..col0+3 per n-tile -> packed stores.
#pragma unroll
  for (int mt = 0; mt < 4; ++mt) {
    const int mrow = (int)m0 + wm * 64 + mt * 16 + r15;
    int win = 0, nn = 0;
    size_t pix = 0;
    if (EPI == EPI_QKV || EPI == EPI_PROJ) {
      win = mrow / 49; nn = mrow - win * 49;
      if (EPI == EPI_PROJ) {
        int b = win >> 6, wh = (win >> 3) & 7, ww = win & 7;
        int i = nn / 7, jj = nn - i * 7;
        int h = wh * 7 + i + 3; if (h >= 56) h -= 56;
        int w = ww * 7 + jj + 3; if (w >= 56) w -= 56;
        pix = (size_t)((b * 56 + h) * 56 + w);
      }
    }
#pragma unroll
    for (int nt = 0; nt < 4; ++nt) {
      const int col0 = n0 + wn * 64 + nt * 16 + g4 * 4;
      f32x4 bv = *(const f32x4*)&bias[col0];
      f32x4 v;
#pragma unroll
      for (int j = 0; j < 4; ++j) v[j] = acc[nt][mt][j] + bv[j];
      if (EPI == EPI_QKV) {
        int s = col0 >> 8, head = (col0 >> 5) & 7, d0 = col0 & 31;
        float sc = (s == 0) ? ATT_SCALE : 1.f;
#pragma unroll
        for (int j = 0; j < 4; ++j) v[j] = fmaxf(v[j], 0.f) * sc;
        uint32_t w0 = (uint32_t)f2b(v[0]) | ((uint32_t)f2b(v[1]) << 16);
        uint32_t w1 = (uint32_t)f2b(v[2]) | ((uint32_t)f2b(v[3]) << 16);
        u16* dst = (u16*)p0 + (size_t)s * ((size_t)NTOK * CC);
        *(uint2*)&dst[(((size_t)(win * NHEAD + head)) * NWT + nn) * HDIM + d0] =
            make_uint2(w0, w1);
      } else if (EPI == EPI_PROJ) {
        f32x4 r = *(const f32x4*)&((const float*)p1)[pix * CC + col0];
#pragma unroll
        for (int j = 0; j < 4; ++j) v[j] += r[j];
        *(f32x4*)&((float*)p0)[pix * CC + col0] = v;
      } else if (EPI == EPI_GELU) {
#pragma unroll
        for (int j = 0; j < 4; ++j)
          v[j] = 0.5f * v[j] * (1.f + erff(v[j] * 0.70710678118654752f));
        uint32_t w0 = (uint32_t)f2b(v[0]) | ((uint32_t)f2b(v[1]) << 16);
        uint32_t w1 = (uint32_t)f2b(v[2]) | ((uint32_t)f2b(v[3]) << 16);
        *(uint2*)&((u16*)p0)[(size_t)mrow * MLPD + col0] = make_uint2(w0, w1);
      } else {  // EPI_FC2
        size_t idx = (size_t)mrow * CC + col0;
        f32x4 r = *(const f32x4*)&((const float*)p1)[idx];
#pragma unroll
        for (int j = 0; j < 4; ++j) v[j] += r[j];
        *(f32x4*)&((float*)p0)[idx] = v;
      }
    }
  }
}

// ---------------- MFMA window attention: 1 wave = 1 (window, head), 4 waves/block
__global__ __launch_bounds__(256)
void attn_mfma_k(const u16* __restrict__ q, const u16* __restrict__ k2,
                 const u16* __restrict__ v2, const float* __restrict__ lut,
                 u16* __restrict__ out) {
  __shared__ u16 P_lds[4][64 * 72];
  const int tid = threadIdx.x;
  const int wv = tid >> 6;
  const int lane = tid & 63;
  const int c = lane & 15;
  const int g = lane >> 4;
  const int blk = blockIdx.x * 4 + wv;   // (window, head) id
  const int head = blk & 7;
  const int win = blk >> 3;
  const int wimg = win & 63;
  const int wh = wimg >> 3, ww = wimg & 7;
  const size_t base = (size_t)blk * (NWT * HDIM);
  u16* Pw = P_lds[wv];

  bf16x8 kf[4], qf[4];
#pragma unroll
  for (int t = 0; t < 4; ++t) {
    kf[t] = *(const bf16x8*)&k2[base + (size_t)(t * 16 + c) * HDIM + g * 8];
    qf[t] = *(const bf16x8*)&q [base + (size_t)(t * 16 + c) * HDIM + g * 8];
  }
  bf16x8 vf[2][2];
#pragma unroll
  for (int kcc = 0; kcc < 2; ++kcc)
#pragma unroll
    for (int td = 0; td < 2; ++td)
#pragma unroll
      for (int jj = 0; jj < 8; ++jj) {
        int m = kcc * 32 + g * 8 + jj;
        m = m < 49 ? m : 48;
        vf[kcc][td][jj] = (short)v2[base + (size_t)m * HDIM + td * 16 + c];
      }

  f32x4 acc[4][4] = {};
#pragma unroll
  for (int tm = 0; tm < 4; ++tm)
#pragma unroll
    for (int tn = 0; tn < 4; ++tn)
      acc[tm][tn] = __builtin_amdgcn_mfma_f32_16x16x32_bf16(kf[tm], qf[tn], acc[tm][tn], 0, 0, 0);

  const float* lrow = &lut[(size_t)head * 64 * 64];
  int Ln[4];
#pragma unroll
  for (int tn = 0; tn < 4; ++tn) {
    int n = tn * 16 + c;
    int i1 = (n * 9363) >> 16;
    int j1 = n - i1 * 7;
    int rh = (wh < 7) ? 0 : (i1 < 4 ? 1 : 2);
    int rw = (ww < 7) ? 0 : (j1 < 4 ? 1 : 2);
    Ln[tn] = rh * 3 + rw;
  }
  float colmax[4] = {0.f, 0.f, 0.f, 0.f};
#pragma unroll
  for (int tm = 0; tm < 4; ++tm)
#pragma unroll
    for (int j = 0; j < 4; ++j) {
      int m = tm * 16 + g * 4 + j;
      int i2 = (m * 9363) >> 16;
      int j2 = m - i2 * 7;
      int rh = (wh < 7) ? 0 : (i2 < 4 ? 1 : 2);
      int rw = (ww < 7) ? 0 : (j2 < 4 ? 1 : 2);
      int Lm = rh * 3 + rw;
#pragma unroll
      for (int tn = 0; tn < 4; ++tn) {
        float s = acc[tm][tn][j] + lrow[m * 64 + tn * 16 + c];
        s = fmaxf(s, 0.f);
        if (Lm != Ln[tn]) s = 0.f;
        acc[tm][tn][j] = s;
        colmax[tn] = fmaxf(colmax[tn], s);
      }
    }
#pragma unroll
  for (int tn = 0; tn < 4; ++tn) {
    colmax[tn] = fmaxf(colmax[tn], __shfl_xor(colmax[tn], 16));
    colmax[tn] = fmaxf(colmax[tn], __shfl_xor(colmax[tn], 32));
  }
  float colsum[4] = {0.f, 0.f, 0.f, 0.f};
#pragma unroll
  for (int tm = 0; tm < 4; ++tm)
#pragma unroll
    for (int j = 0; j < 4; ++j) {
      int m = tm * 16 + g * 4 + j;
      bool mvalid = (m < NWT);
#pragma unroll
      for (int tn = 0; tn < 4; ++tn) {
        float e = mvalid ? __expf(acc[tm][tn][j] - colmax[tn]) : 0.f;
        acc[tm][tn][j] = e;
        colsum[tn] += e;
      }
    }
#pragma unroll
  for (int tn = 0; tn < 4; ++tn) {
    colsum[tn] += __shfl_xor(colsum[tn], 16);
    colsum[tn] += __shfl_xor(colsum[tn], 32);
    colsum[tn] = 1.f / colsum[tn];
  }

#pragma unroll
  for (int tn = 0; tn < 4; ++tn) {
    int n = tn * 16 + c;
#pragma unroll
    for (int tm = 0; tm < 4; ++tm) {
      float r = colsum[tn];
      uint32_t w0 = (uint32_t)f2b(acc[tm][tn][0] * r) | ((uint32_t)f2b(acc[tm][tn][1] * r) << 16);
      uint32_t w1 = (uint32_t)f2b(acc[tm][tn][2] * r) | ((uint32_t)f2b(acc[tm][tn][3] * r) << 16);
      *(uint2*)&Pw[n * 72 + tm * 16 + g * 4] = make_uint2(w0, w1);
    }
  }

  f32x4 oacc[4][2] = {};
#pragma unroll
  for (int kcc = 0; kcc < 2; ++kcc) {
    bf16x8 pf[4];
#pragma unroll
    for (int tr = 0; tr < 4; ++tr)
      pf[tr] = *(const bf16x8*)&Pw[(tr * 16 + c) * 72 + kcc * 32 + g * 8];
#pragma unroll
    for (int tr = 0; tr < 4; ++tr)
#pragma unroll
      for (int td = 0; td < 2; ++td)
        oacc[tr][td] = __builtin_amdgcn_mfma_f32_16x16x32_bf16(pf[tr], vf[kcc][td], oacc[tr][td], 0, 0, 0);
  }

#pragma unroll
  for (int tr = 0; tr < 4; ++tr)
#pragma unroll
    for (int j = 0; j < 4; ++j) {
      int n = tr * 16 + g * 4 + j;
      if (n < NWT) {
#pragma unroll
        for (int td = 0; td < 2; ++td) {
          int d = td * 16 + c;
          out[((size_t)(win * NWT + n)) * CC + head * HDIM + d] =
              f2b(fmaxf(oacc[tr][td][j], 0.f));
        }
      }
    }
}

// ---------------- launch
extern "C" void kernel_launch(void* const* d_in, const int* in_sizes, int n_in,
                              void* d_out, int out_size, void* d_ws, size_t ws_size,
                              hipStream_t stream) {
  const float* x      = (const float*)d_in[0];
  const float* gamma1 = (const float*)d_in[1];
  const float* beta1  = (const float*)d_in[2];
  const float* w_qkv  = (const float*)d_in[3];
  const float* b_qkv  = (const float*)d_in[4];
  const float* rpb    = (const float*)d_in[5];
  const float* w_proj = (const float*)d_in[6];
  const float* b_proj = (const float*)d_in[7];
  const float* gamma2 = (const float*)d_in[8];
  const float* beta2  = (const float*)d_in[9];
  const float* w_fc1  = (const float*)d_in[10];
  const float* b_fc1  = (const float*)d_in[11];
  const float* w_fc2  = (const float*)d_in[12];
  const float* b_fc2  = (const float*)d_in[13];
  float* out = (float*)d_out;

  char* ws = (char*)d_ws;
  size_t off = 0;
  auto alloc = [&](size_t bytes) { void* p = ws + off; off = (off + bytes + 255) & ~(size_t)255; return p; };

  u16* wqkvT = (u16*)alloc(768 * 256 * 2);
  u16* wprojT = (u16*)alloc(256 * 256 * 2);
  u16* wfc1T = (u16*)alloc(1024 * 256 * 2);
  u16* wfc2T = (u16*)alloc(256 * 1024 * 2);
  float* lut = (float*)alloc(8 * 64 * 64 * 4);
  // region2: xw -> attn_out -> xn2 (lifetimes disjoint)
  u16* region2 = (u16*)alloc((size_t)NTOK * CC * 2);
  // region1: q|k|v (3x 51.4MB); later x2 (fp32, 102.8MB) + h chunk (51.4MB) = exact fit
  char* region1 = (char*)alloc((size_t)3 * NTOK * CC * 2);

  u16* xw = region2;
  u16* qb = (u16*)region1;
  u16* kb = qb + (size_t)NTOK * CC;
  u16* vb = kb + (size_t)NTOK * CC;
  u16* attn_out = region2;
  float* x2 = (float*)region1;
  u16* xn2 = region2;
  u16* hbuf = (u16*)(region1 + (size_t)NTOK * CC * 4);  // after x2's 102.8MB

  if (ws_size < off) return;  // insufficient scratch: fail visibly

  wconv_k<<<(256 * 768 + 255) / 256, 256, 0, stream>>>(w_qkv, wqkvT, 256, 768);
  wconv_k<<<(256 * 256 + 255) / 256, 256, 0, stream>>>(w_proj, wprojT, 256, 256);
  wconv_k<<<(256 * 1024 + 255) / 256, 256, 0, stream>>>(w_fc1, wfc1T, 256, 1024);
  wconv_k<<<(1024 * 256 + 255) / 256, 256, 0, stream>>>(w_fc2, wfc2T, 1024, 256);
  bias_lut_k<<<(8 * 64 * 64) / 256, 256, 0, stream>>>(rpb, lut);

  // LN1 + shift + partition
  ln_k<true><<<NTOK / 4, 256, 0, stream>>>(x, gamma1, beta1, xw);

  // QKV GEMM: M=100352, N=768, K=256 (counted-vmcnt pipeline, packed epilogue)
  gemm_k<EPI_QKV, 4><<<dim3(768 / BN, NTOK / BM), 256, 0, stream>>>(
      xw, wqkvT, b_qkv, (void*)qb, nullptr);

  // fused MFMA window attention: 1 wave per (window, head)
  attn_mfma_k<<<NWIN * NHEAD / 4, 256, 0, stream>>>(qb, kb, vb, lut, attn_out);

  // proj GEMM + reverse shift + residual: M=100352, N=256, K=256
  gemm_k<EPI_PROJ, 4><<<dim3(256 / BN, NTOK / BM), 256, 0, stream>>>(
      attn_out, wprojT, b_proj, (void*)x2, (const void*)x);

  // LN2
  ln_k<false><<<NTOK / 4, 256, 0, stream>>>(x2, gamma2, beta2, xn2);

  // MLP in 4 M-chunks of 25088 rows (h chunk 51.4MB, fits region1 tail exactly)
  const int MCH = 25088;
  for (int c = 0; c < 4; ++c) {
    const u16* a1 = xn2 + (size_t)c * MCH * CC;
    gemm_k<EPI_GELU, 4><<<dim3(MLPD / BN, MCH / BM), 256, 0, stream>>>(
        a1, wfc1T, b_fc1, (void*)hbuf, nullptr);
    gemm_k<EPI_FC2, 16><<<dim3(CC / BN, MCH / BM), 256, 0, stream>>>(
        hbuf, wfc2T, b_fc2, (void*)(out + (size_t)c * MCH * CC),
        (const void*)(x2 + (size_t)c * MCH * CC));
  }
}

// Round 9
// 514.179 us; speedup vs baseline: 1.6588x; 1.0047x over previous
//
#include <hip/hip_runtime.h>
#include <stdint.h>

typedef unsigned short u16;
typedef short bf16x8 __attribute__((ext_vector_type(8)));
typedef float f32x4 __attribute__((ext_vector_type(4)));

#define NTOK 100352      // B*H*W tokens
#define NWIN 2048        // B * 64 windows
#define CC 256
#define NHEAD 8
#define HDIM 32
#define NWT 49           // tokens per window
#define MLPD 1024
#define ATT_SCALE 0.17677669529663687f  // 32^-0.5

__device__ __forceinline__ u16 f2b(float f) {
  union { float f; uint32_t u; } c; c.f = f;
  return (u16)((c.u + 0x7fffu + ((c.u >> 16) & 1u)) >> 16);
}
__device__ __forceinline__ float b2f(u16 h) {
  union { uint32_t u; float f; } c; c.u = ((uint32_t)h) << 16;
  return c.f;
}
// packed f32x2 -> bf16x2 (RNE), 1 VALU op
__device__ __forceinline__ uint32_t f2b2(float lo, float hi) {
  uint32_t r;
  asm("v_cvt_pk_bf16_f32 %0, %1, %2" : "=v"(r) : "v"(lo), "v"(hi));
  return r;
}

__device__ __forceinline__ void gload_lds16(const void* g, void* l) {
  __builtin_amdgcn_global_load_lds((const __attribute__((address_space(1))) void*)g,
                                   (__attribute__((address_space(3))) void*)l, 16, 0, 0);
}

// ---------------- prep: all weight transposes + bias LUT in ONE dispatch
__global__ __launch_bounds__(256)
void prep_k(const float* __restrict__ wqkv, const float* __restrict__ wproj,
            const float* __restrict__ wfc1, const float* __restrict__ wfc2,
            const float* __restrict__ rpb,
            u16* __restrict__ qkvT, u16* __restrict__ projT,
            u16* __restrict__ fc1T, u16* __restrict__ fc2T, float* __restrict__ lut) {
  int i = blockIdx.x * 256 + threadIdx.x;
  if (i < 196608) {                     // wqkv: K=256, N=768
    int k = i / 768, n = i % 768;
    qkvT[(size_t)n * 256 + k] = f2b(wqkv[i]);
  } else if (i < 262144) {              // wproj: 256x256
    int j = i - 196608, k = j / 256, n = j % 256;
    projT[(size_t)n * 256 + k] = f2b(wproj[j]);
  } else if (i < 524288) {              // wfc1: K=256, N=1024
    int j = i - 262144, k = j / 1024, n = j % 1024;
    fc1T[(size_t)n * 256 + k] = f2b(wfc1[j]);
  } else if (i < 786432) {              // wfc2: K=1024, N=256
    int j = i - 524288, k = j / 256, n = j % 256;
    fc2T[(size_t)n * 1024 + k] = f2b(wfc2[j]);
  } else if (i < 819200) {              // bias LUT lut[h][m][n], 64x64 padded
    int j = i - 786432;
    int h = j >> 12, m = (j >> 6) & 63, n = j & 63;
    float v = 0.f;
    if (m < 49 && n < 49) {
      int i1 = n / 7, j1 = n % 7, i2 = m / 7, j2 = m % 7;
      v = rpb[((i1 - i2 + 6) * 13 + (j1 - j2 + 6)) * 8 + h];
    }
    lut[j] = v;
  }
}

// ---------------- LN1 + cyclic-shift + window-partition -> bf16 tokens
__global__ __launch_bounds__(256)
void ln_k(const float* __restrict__ x, const float* __restrict__ g,
          const float* __restrict__ be, u16* __restrict__ out) {
  int token = blockIdx.x * 4 + (threadIdx.x >> 6);
  int lane = threadIdx.x & 63;
  int win = token / 49, nn = token % 49;
  int b = win >> 6, wh = (win >> 3) & 7, ww = win & 7;
  int i = nn / 7, j = nn % 7;
  int h = wh * 7 + i + 3; if (h >= 56) h -= 56;
  int w = ww * 7 + j + 3; if (w >= 56) w -= 56;
  size_t src = ((size_t)((b * 56 + h) * 56 + w)) * CC;
  f32x4 v = *(const f32x4*)&x[src + lane * 4];
  float s1 = v[0] + v[1] + v[2] + v[3];
  float s2 = v[0]*v[0] + v[1]*v[1] + v[2]*v[2] + v[3]*v[3];
#pragma unroll
  for (int o = 32; o; o >>= 1) { s1 += __shfl_xor(s1, o); s2 += __shfl_xor(s2, o); }
  float mean = s1 * (1.f / 256.f);
  float var = s2 * (1.f / 256.f) - mean * mean;
  float rstd = rsqrtf(var + 1e-5f);
  f32x4 gv = *(const f32x4*)&g[lane * 4];
  f32x4 bv = *(const f32x4*)&be[lane * 4];
  float y0 = (v[0]-mean)*rstd*gv[0] + bv[0];
  float y1 = (v[1]-mean)*rstd*gv[1] + bv[1];
  float y2 = (v[2]-mean)*rstd*gv[2] + bv[2];
  float y3 = (v[3]-mean)*rstd*gv[3] + bv[3];
  *(uint2*)&out[(size_t)token * CC + lane * 4] = make_uint2(f2b2(y0, y1), f2b2(y2, y3));
}

// ---------------- GEMM (128x128): counted-vmcnt pipeline + C^T packed epilogue
#define BM 128
#define BN 128
#define BK 64
enum { EPI_QKV = 0, EPI_GELU = 2, EPI_FC2 = 3 };

template<int EPI, int NKT>
__global__ __launch_bounds__(256)
void gemm_k(const u16* __restrict__ A, const u16* __restrict__ BT,
            const float* __restrict__ bias,
            void* __restrict__ p0, const void* __restrict__ p1) {
  constexpr int K = NKT * BK;
  __shared__ u16 aL[2][BM * BK];
  __shared__ u16 bL[2][BN * BK];
  const int tid = threadIdx.x;
  const int lane = tid & 63;
  const int wv = tid >> 6;
  const int wm = wv >> 1, wn = wv & 1;

  int bx = blockIdx.x, by = blockIdx.y;
  {
    int nwg = gridDim.x * gridDim.y;
    int lin = by * gridDim.x + bx;
    int q = nwg >> 3, r = nwg & 7;
    int xcd = lin & 7, idx = lin >> 3;
    int wg = (xcd < r ? xcd * (q + 1) : r * (q + 1) + (xcd - r) * q) + idx;
    bx = wg % gridDim.x;
    by = wg / gridDim.x;
  }
  const long m0 = (long)by * BM;
  const int n0 = bx * BN;

  f32x4 acc[4][4] = {};   // [n-tile][m-tile]
  const int r15 = lane & 15;
  const int g4 = lane >> 4;

  const u16* pA[4];
  const u16* pB[4];
  int lslot[4];
#pragma unroll
  for (int it = 0; it < 4; ++it) {
    int slot = tid + 256 * it;
    int row = slot >> 3, c8 = slot & 7;
    int cs = c8 ^ (row & 7);
    pA[it] = &A[(m0 + row) * K + cs * 8];
    pB[it] = &BT[(size_t)(n0 + row) * K + cs * 8];
    lslot[it] = slot * 8;
  }
  int aoff[2][4], boff[2][4];
#pragma unroll
  for (int kk = 0; kk < 2; ++kk)
#pragma unroll
    for (int m = 0; m < 4; ++m) {
      int rowa = wm * 64 + m * 16 + r15;
      aoff[kk][m] = rowa * BK + (((kk * 4 + g4) ^ (rowa & 7)) << 3);
      int rowb = wn * 64 + m * 16 + r15;
      boff[kk][m] = rowb * BK + (((kk * 4 + g4) ^ (rowb & 7)) << 3);
    }

  auto stage = [&](int bufi) {
#pragma unroll
    for (int it = 0; it < 4; ++it) { gload_lds16(pA[it], &aL[bufi][lslot[it]]); pA[it] += BK; }
#pragma unroll
    for (int it = 0; it < 4; ++it) { gload_lds16(pB[it], &bL[bufi][lslot[it]]); pB[it] += BK; }
  };

  stage(0);
  stage(1);

#pragma unroll
  for (int t = 0; t < NKT; ++t) {
    if (t + 1 < NKT) asm volatile("s_waitcnt vmcnt(8)" ::: "memory");
    else             asm volatile("s_waitcnt vmcnt(0)" ::: "memory");
    __builtin_amdgcn_sched_barrier(0);
    __builtin_amdgcn_s_barrier();
    __builtin_amdgcn_sched_barrier(0);
    {
      const u16* ab = aL[t & 1];
      const u16* bb = bL[t & 1];
#pragma unroll
      for (int kk = 0; kk < 2; ++kk) {
        bf16x8 af[4], bfr[4];
#pragma unroll
        for (int m = 0; m < 4; ++m) af[m] = *(const bf16x8*)&ab[aoff[kk][m]];
#pragma unroll
        for (int n = 0; n < 4; ++n) bfr[n] = *(const bf16x8*)&bb[boff[kk][n]];
#pragma unroll
        for (int n = 0; n < 4; ++n)
#pragma unroll
          for (int m = 0; m < 4; ++m)
            acc[n][m] = __builtin_amdgcn_mfma_f32_16x16x32_bf16(bfr[n], af[m], acc[n][m], 0, 0, 0);
      }
    }
    __builtin_amdgcn_sched_barrier(0);
    __builtin_amdgcn_s_barrier();
    __builtin_amdgcn_sched_barrier(0);
    if (t + 2 < NKT) stage(t & 1);
  }

  // epilogue (C^T): lane holds row mrow fixed, 4 consecutive cols per n-tile
#pragma unroll
  for (int mt = 0; mt < 4; ++mt) {
    const int mrow = (int)m0 + wm * 64 + mt * 16 + r15;
    int win = 0, nn = 0;
    if (EPI == EPI_QKV) { win = mrow / 49; nn = mrow - win * 49; }
#pragma unroll
    for (int nt = 0; nt < 4; ++nt) {
      const int col0 = n0 + wn * 64 + nt * 16 + g4 * 4;
      f32x4 bv = *(const f32x4*)&bias[col0];
      f32x4 v;
#pragma unroll
      for (int j = 0; j < 4; ++j) v[j] = acc[nt][mt][j] + bv[j];
      if (EPI == EPI_QKV) {
        int s = col0 >> 8, head = (col0 >> 5) & 7, d0 = col0 & 31;
        float sc = (s == 0) ? ATT_SCALE : 1.f;
#pragma unroll
        for (int j = 0; j < 4; ++j) v[j] = fmaxf(v[j], 0.f) * sc;
        u16* dst = (u16*)p0 + (size_t)s * ((size_t)NTOK * CC);
        *(uint2*)&dst[(((size_t)(win * NHEAD + head)) * NWT + nn) * HDIM + d0] =
            make_uint2(f2b2(v[0], v[1]), f2b2(v[2], v[3]));
      } else if (EPI == EPI_GELU) {
#pragma unroll
        for (int j = 0; j < 4; ++j) {
          float u = 0.79788456f * (v[j] + 0.044715f * v[j] * v[j] * v[j]);
          float th = 1.f - 2.f / (__expf(2.f * u) + 1.f);   // NaN-safe tanh
          v[j] = 0.5f * v[j] * (1.f + th);
        }
        *(uint2*)&((u16*)p0)[(size_t)mrow * MLPD + col0] =
            make_uint2(f2b2(v[0], v[1]), f2b2(v[2], v[3]));
      } else {  // EPI_FC2
        size_t idx = (size_t)mrow * CC + col0;
        f32x4 r = *(const f32x4*)&((const float*)p1)[idx];
#pragma unroll
        for (int j = 0; j < 4; ++j) v[j] += r[j];
        *(f32x4*)&((float*)p0)[idx] = v;
      }
    }
  }
}

// ---------------- PROJ GEMM (256x256, 512 thr) + reverse-shift residual + FUSED LN2
// Block covers full 256-col rows -> per-row LN stats in epilogue (shfl + LDS exchange).
__global__ __launch_bounds__(512)
void gemm_ln_k(const u16* __restrict__ A, const u16* __restrict__ BT,
               const float* __restrict__ bias, const float* __restrict__ xres,
               const float* __restrict__ g2, const float* __restrict__ be2,
               float* __restrict__ x2, u16* __restrict__ xn2) {
  constexpr int K = 256;
  __shared__ u16 aL[2][256 * 64];
  __shared__ u16 bL[2][256 * 64];
  const int tid = threadIdx.x;
  const int lane = tid & 63;
  const int wv = tid >> 6;
  const int wm = wv >> 1;     // 0..3: 64 rows each
  const int wn = wv & 1;      // 0..1: 128 cols each
  const int r15 = lane & 15;
  const int g4 = lane >> 4;

  int by = blockIdx.x;
  {
    int nwg = gridDim.x;
    int q = nwg >> 3, r = nwg & 7;
    int xcd = by & 7, idx = by >> 3;
    by = (xcd < r ? xcd * (q + 1) : r * (q + 1) + (xcd - r) * q) + idx;
  }
  const long m0 = (long)by * 256;

  f32x4 acc[8][4] = {};   // [n-tile 0..7][m-tile 0..3]

  const u16* pA[4];
  const u16* pB[4];
  int lslot[4];
#pragma unroll
  for (int it = 0; it < 4; ++it) {
    int slot = tid + 512 * it;          // 2048 slots over 512 threads
    int row = slot >> 3, c8 = slot & 7;
    int cs = c8 ^ (row & 7);
    pA[it] = &A[(m0 + row) * K + cs * 8];
    pB[it] = &BT[(size_t)row * K + cs * 8];
    lslot[it] = slot * 8;
  }
  int aoff[2][4], boff[2][8];
#pragma unroll
  for (int kk = 0; kk < 2; ++kk) {
#pragma unroll
    for (int m = 0; m < 4; ++m) {
      int rowa = wm * 64 + m * 16 + r15;
      aoff[kk][m] = rowa * BK + (((kk * 4 + g4) ^ (rowa & 7)) << 3);
    }
#pragma unroll
    for (int n = 0; n < 8; ++n) {
      int rowb = wn * 128 + n * 16 + r15;
      boff[kk][n] = rowb * BK + (((kk * 4 + g4) ^ (rowb & 7)) << 3);
    }
  }

  auto stage = [&](int bufi) {
#pragma unroll
    for (int it = 0; it < 4; ++it) { gload_lds16(pA[it], &aL[bufi][lslot[it]]); pA[it] += BK; }
#pragma unroll
    for (int it = 0; it < 4; ++it) { gload_lds16(pB[it], &bL[bufi][lslot[it]]); pB[it] += BK; }
  };

  stage(0);
  stage(1);

#pragma unroll
  for (int t = 0; t < 4; ++t) {
    if (t + 1 < 4) asm volatile("s_waitcnt vmcnt(8)" ::: "memory");
    else           asm volatile("s_waitcnt vmcnt(0)" ::: "memory");
    __builtin_amdgcn_sched_barrier(0);
    __builtin_amdgcn_s_barrier();
    __builtin_amdgcn_sched_barrier(0);
    {
      const u16* ab = aL[t & 1];
      const u16* bb = bL[t & 1];
#pragma unroll
      for (int kk = 0; kk < 2; ++kk) {
        bf16x8 af[4], bfr[8];
#pragma unroll
        for (int m = 0; m < 4; ++m) af[m] = *(const bf16x8*)&ab[aoff[kk][m]];
#pragma unroll
        for (int n = 0; n < 8; ++n) bfr[n] = *(const bf16x8*)&bb[boff[kk][n]];
#pragma unroll
        for (int n = 0; n < 8; ++n)
#pragma unroll
          for (int m = 0; m < 4; ++m)
            acc[n][m] = __builtin_amdgcn_mfma_f32_16x16x32_bf16(bfr[n], af[m], acc[n][m], 0, 0, 0);
      }
    }
    __builtin_amdgcn_sched_barrier(0);
    __builtin_amdgcn_s_barrier();
    __builtin_amdgcn_sched_barrier(0);
    if (t + 2 < 4) stage(t & 1);
  }

  // ---- epilogue: v = x + proj + bias -> x2; per-row LN -> xn2
  float* st = (float*)&aL[0][0];        // stats [wn][256 rows][2], aL is free now
  size_t pix[4];
  float s1[4] = {}, s2[4] = {};
#pragma unroll
  for (int mt = 0; mt < 4; ++mt) {
    const int mrow = (int)m0 + wm * 64 + mt * 16 + r15;
    int win = mrow / 49, nn = mrow - win * 49;
    int b = win >> 6, wh = (win >> 3) & 7, ww = win & 7;
    int i = nn / 7, jj = nn - i * 7;
    int h = wh * 7 + i + 3; if (h >= 56) h -= 56;
    int w = ww * 7 + jj + 3; if (w >= 56) w -= 56;
    pix[mt] = (size_t)((b * 56 + h) * 56 + w);
#pragma unroll
    for (int nt = 0; nt < 8; ++nt) {
      const int col0 = wn * 128 + nt * 16 + g4 * 4;
      f32x4 bv = *(const f32x4*)&bias[col0];
      f32x4 r = *(const f32x4*)&xres[pix[mt] * CC + col0];
      f32x4 v;
#pragma unroll
      for (int j = 0; j < 4; ++j) {
        v[j] = acc[nt][mt][j] + bv[j] + r[j];
        s1[mt] += v[j];
        s2[mt] += v[j] * v[j];
      }
      *(f32x4*)&x2[pix[mt] * CC + col0] = v;
      acc[nt][mt] = v;                   // keep for LN pass
    }
    s1[mt] += __shfl_xor(s1[mt], 16);  s1[mt] += __shfl_xor(s1[mt], 32);
    s2[mt] += __shfl_xor(s2[mt], 16);  s2[mt] += __shfl_xor(s2[mt], 32);
    if (g4 == 0) {
      int wrow = wm * 64 + mt * 16 + r15;
      st[(wn * 256 + wrow) * 2 + 0] = s1[mt];
      st[(wn * 256 + wrow) * 2 + 1] = s2[mt];
    }
  }
  __syncthreads();
#pragma unroll
  for (int mt = 0; mt < 4; ++mt) {
    int wrow = wm * 64 + mt * 16 + r15;
    float t1 = s1[mt] + st[((wn ^ 1) * 256 + wrow) * 2 + 0];
    float t2 = s2[mt] + st[((wn ^ 1) * 256 + wrow) * 2 + 1];
    float mean = t1 * (1.f / 256.f);
    float var = t2 * (1.f / 256.f) - mean * mean;
    float rstd = rsqrtf(var + 1e-5f);
#pragma unroll
    for (int nt = 0; nt < 8; ++nt) {
      const int col0 = wn * 128 + nt * 16 + g4 * 4;
      f32x4 gv = *(const f32x4*)&g2[col0];
      f32x4 bv = *(const f32x4*)&be2[col0];
      float y0 = (acc[nt][mt][0] - mean) * rstd * gv[0] + bv[0];
      float y1 = (acc[nt][mt][1] - mean) * rstd * gv[1] + bv[1];
      float y2 = (acc[nt][mt][2] - mean) * rstd * gv[2] + bv[2];
      float y3 = (acc[nt][mt][3] - mean) * rstd * gv[3] + bv[3];
      *(uint2*)&xn2[pix[mt] * CC + col0] = make_uint2(f2b2(y0, y1), f2b2(y2, y3));
    }
  }
}

// ---------------- MFMA window attention: 1 wave = 1 (window, head), 4 waves/block
__global__ __launch_bounds__(256)
void attn_mfma_k(const u16* __restrict__ q, const u16* __restrict__ k2,
                 const u16* __restrict__ v2, const float* __restrict__ lut,
                 u16* __restrict__ out) {
  __shared__ u16 P_lds[4][64 * 72];
  const int tid = threadIdx.x;
  const int wv = tid >> 6;
  const int lane = tid & 63;
  const int c = lane & 15;
  const int g = lane >> 4;
  const int blk = blockIdx.x * 4 + wv;
  const int head = blk & 7;
  const int win = blk >> 3;
  const int wimg = win & 63;
  const int wh = wimg >> 3, ww = wimg & 7;
  const size_t base = (size_t)blk * (NWT * HDIM);
  u16* Pw = P_lds[wv];

  bf16x8 kf[4], qf[4];
#pragma unroll
  for (int t = 0; t < 4; ++t) {
    kf[t] = *(const bf16x8*)&k2[base + (size_t)(t * 16 + c) * HDIM + g * 8];
    qf[t] = *(const bf16x8*)&q [base + (size_t)(t * 16 + c) * HDIM + g * 8];
  }
  bf16x8 vf[2][2];
#pragma unroll
  for (int kcc = 0; kcc < 2; ++kcc)
#pragma unroll
    for (int td = 0; td < 2; ++td)
#pragma unroll
      for (int jj = 0; jj < 8; ++jj) {
        int m = kcc * 32 + g * 8 + jj;
        m = m < 49 ? m : 48;
        vf[kcc][td][jj] = (short)v2[base + (size_t)m * HDIM + td * 16 + c];
      }

  f32x4 acc[4][4] = {};
#pragma unroll
  for (int tm = 0; tm < 4; ++tm)
#pragma unroll
    for (int tn = 0; tn < 4; ++tn)
      acc[tm][tn] = __builtin_amdgcn_mfma_f32_16x16x32_bf16(kf[tm], qf[tn], acc[tm][tn], 0, 0, 0);

  const float* lrow = &lut[(size_t)head * 64 * 64];
  int Ln[4];
#pragma unroll
  for (int tn = 0; tn < 4; ++tn) {
    int n = tn * 16 + c;
    int i1 = (n * 9363) >> 16;
    int j1 = n - i1 * 7;
    int rh = (wh < 7) ? 0 : (i1 < 4 ? 1 : 2);
    int rw = (ww < 7) ? 0 : (j1 < 4 ? 1 : 2);
    Ln[tn] = rh * 3 + rw;
  }
  float colmax[4] = {0.f, 0.f, 0.f, 0.f};
#pragma unroll
  for (int tm = 0; tm < 4; ++tm)
#pragma unroll
    for (int j = 0; j < 4; ++j) {
      int m = tm * 16 + g * 4 + j;
      int i2 = (m * 9363) >> 16;
      int j2 = m - i2 * 7;
      int rh = (wh < 7) ? 0 : (i2 < 4 ? 1 : 2);
      int rw = (ww < 7) ? 0 : (j2 < 4 ? 1 : 2);
      int Lm = rh * 3 + rw;
#pragma unroll
      for (int tn = 0; tn < 4; ++tn) {
        float s = acc[tm][tn][j] + lrow[m * 64 + tn * 16 + c];
        s = fmaxf(s, 0.f);
        if (Lm != Ln[tn]) s = 0.f;
        acc[tm][tn][j] = s;
        colmax[tn] = fmaxf(colmax[tn], s);
      }
    }
#pragma unroll
  for (int tn = 0; tn < 4; ++tn) {
    colmax[tn] = fmaxf(colmax[tn], __shfl_xor(colmax[tn], 16));
    colmax[tn] = fmaxf(colmax[tn], __shfl_xor(colmax[tn], 32));
  }
  float colsum[4] = {0.f, 0.f, 0.f, 0.f};
#pragma unroll
  for (int tm = 0; tm < 4; ++tm)
#pragma unroll
    for (int j = 0; j < 4; ++j) {
      int m = tm * 16 + g * 4 + j;
      bool mvalid = (m < NWT);
#pragma unroll
      for (int tn = 0; tn < 4; ++tn) {
        float e = mvalid ? __expf(acc[tm][tn][j] - colmax[tn]) : 0.f;
        acc[tm][tn][j] = e;
        colsum[tn] += e;
      }
    }
#pragma unroll
  for (int tn = 0; tn < 4; ++tn) {
    colsum[tn] += __shfl_xor(colsum[tn], 16);
    colsum[tn] += __shfl_xor(colsum[tn], 32);
    colsum[tn] = 1.f / colsum[tn];
  }

#pragma unroll
  for (int tn = 0; tn < 4; ++tn) {
    int n = tn * 16 + c;
#pragma unroll
    for (int tm = 0; tm < 4; ++tm) {
      float r = colsum[tn];
      *(uint2*)&Pw[n * 72 + tm * 16 + g * 4] =
          make_uint2(f2b2(acc[tm][tn][0] * r, acc[tm][tn][1] * r),
                     f2b2(acc[tm][tn][2] * r, acc[tm][tn][3] * r));
    }
  }

  f32x4 oacc[4][2] = {};
#pragma unroll
  for (int kcc = 0; kcc < 2; ++kcc) {
    bf16x8 pf[4];
#pragma unroll
    for (int tr = 0; tr < 4; ++tr)
      pf[tr] = *(const bf16x8*)&Pw[(tr * 16 + c) * 72 + kcc * 32 + g * 8];
#pragma unroll
    for (int tr = 0; tr < 4; ++tr)
#pragma unroll
      for (int td = 0; td < 2; ++td)
        oacc[tr][td] = __builtin_amdgcn_mfma_f32_16x16x32_bf16(pf[tr], vf[kcc][td], oacc[tr][td], 0, 0, 0);
  }

#pragma unroll
  for (int tr = 0; tr < 4; ++tr)
#pragma unroll
    for (int j = 0; j < 4; ++j) {
      int n = tr * 16 + g * 4 + j;
      if (n < NWT) {
#pragma unroll
        for (int td = 0; td < 2; ++td) {
          int d = td * 16 + c;
          out[((size_t)(win * NWT + n)) * CC + head * HDIM + d] =
              f2b(fmaxf(oacc[tr][td][j], 0.f));
        }
      }
    }
}

// ---------------- launch
extern "C" void kernel_launch(void* const* d_in, const int* in_sizes, int n_in,
                              void* d_out, int out_size, void* d_ws, size_t ws_size,
                              hipStream_t stream) {
  const float* x      = (const float*)d_in[0];
  const float* gamma1 = (const float*)d_in[1];
  const float* beta1  = (const float*)d_in[2];
  const float* w_qkv  = (const float*)d_in[3];
  const float* b_qkv  = (const float*)d_in[4];
  const float* rpb    = (const float*)d_in[5];
  const float* w_proj = (const float*)d_in[6];
  const float* b_proj = (const float*)d_in[7];
  const float* gamma2 = (const float*)d_in[8];
  const float* beta2  = (const float*)d_in[9];
  const float* w_fc1  = (const float*)d_in[10];
  const float* b_fc1  = (const float*)d_in[11];
  const float* w_fc2  = (const float*)d_in[12];
  const float* b_fc2  = (const float*)d_in[13];
  float* out = (float*)d_out;

  char* ws = (char*)d_ws;
  size_t off = 0;
  auto alloc = [&](size_t bytes) { void* p = ws + off; off = (off + bytes + 255) & ~(size_t)255; return p; };

  u16* wqkvT = (u16*)alloc(768 * 256 * 2);
  u16* wprojT = (u16*)alloc(256 * 256 * 2);
  u16* wfc1T = (u16*)alloc(1024 * 256 * 2);
  u16* wfc2T = (u16*)alloc(256 * 1024 * 2);
  float* lut = (float*)alloc(8 * 64 * 64 * 4);
  // region2 (51.4MB): xw -> attn_out -> hbuf   (strictly sequential lifetimes)
  u16* region2 = (u16*)alloc((size_t)NTOK * CC * 2);
  // region1 (154.2MB): q|k|v  ->  x2 (102.8MB fp32) + xn2 (51.4MB bf16)
  char* region1 = (char*)alloc((size_t)3 * NTOK * CC * 2);

  u16* xw = region2;
  u16* qb = (u16*)region1;
  u16* kb = qb + (size_t)NTOK * CC;
  u16* vb = kb + (size_t)NTOK * CC;
  u16* attn_out = region2;
  float* x2 = (float*)region1;
  u16* xn2 = (u16*)(region1 + (size_t)NTOK * CC * 4);
  u16* hbuf = region2;

  if (ws_size < off) return;

  prep_k<<<3200, 256, 0, stream>>>(w_qkv, w_proj, w_fc1, w_fc2, rpb,
                                   wqkvT, wprojT, wfc1T, wfc2T, lut);

  // LN1 + shift + partition
  ln_k<<<NTOK / 4, 256, 0, stream>>>(x, gamma1, beta1, xw);

  // QKV GEMM: M=100352, N=768, K=256
  gemm_k<EPI_QKV, 4><<<dim3(768 / BN, NTOK / BM), 256, 0, stream>>>(
      xw, wqkvT, b_qkv, (void*)qb, nullptr);

  // fused MFMA window attention
  attn_mfma_k<<<NWIN * NHEAD / 4, 256, 0, stream>>>(qb, kb, vb, lut, attn_out);

  // PROJ (256x256 tile) + reverse-shift residual + fused LN2
  gemm_ln_k<<<NTOK / 256, 512, 0, stream>>>(
      attn_out, wprojT, b_proj, x, gamma2, beta2, x2, xn2);

  // MLP in 4 M-chunks of 25088 rows (h chunk 51.4MB in region2)
  const int MCH = 25088;
  for (int c = 0; c < 4; ++c) {
    const u16* a1 = xn2 + (size_t)c * MCH * CC;
    gemm_k<EPI_GELU, 4><<<dim3(MLPD / BN, MCH / BM), 256, 0, stream>>>(
        a1, wfc1T, b_fc1, (void*)hbuf, nullptr);
    gemm_k<EPI_FC2, 16><<<dim3(CC / BN, MCH / BM), 256, 0, stream>>>(
        hbuf, wfc2T, b_fc2, (void*)(out + (size_t)c * MCH * CC),
        (const void*)(x2 + (size_t)c * MCH * CC));
  }
}